// Round 6
// baseline (211.755 us; speedup 1.0000x reference)
//
#include <hip/hip_runtime.h>

// Problem constants (fixed by reference: x is (2, 4, 128, 128, 128) fp32)
#define NBATCH 2
#define NDIM   128
#define NP     (128 * 128 * 128)        // particles per batch = mesh cells (2^21)
#define DIS_NORM 3.072f                  // 6 * 512 / 1000

// Tiling: 16^3 origin tiles; LDS window halo LO=5 below, HI=6 above.
// WIN=27 -> 19683 cells as PACKED u64 pairs (2 cells/word), 2^-24 fixed point,
// native u64 LDS atomics (fp32 LDS atomicAdd is a CAS loop: 2.7x slower,
// measured r3; WIN=23 spill blowup: +47us, measured r4). ~81.3 KB LDS ->
// 2 blocks/CU. Window is flushed straight to out with coalesced global f32
// atomics (slab inbox + gather kernel removed: they were a 4.8x traffic
// amplification -- 196 MB of HBM for a 16.8 MB output).
#define TS   16
#define LO   5
#define HI   6
#define WIN  (TS + LO + HI)              // 27
#define WIN2 (WIN * WIN)                 // 729
#define WINF (WIN * WIN * WIN)           // 19683
#define TPB  8
#define NTILE (TPB * TPB * TPB)          // 512 tiles per batch
#define NTHR 512

#define FXSCALE 16777216.0f              // 2^24
#define FXINV   (1.0f / 16777216.0f)

// Spill queue: expected ~98 slow particles/block (2.4% of 4096); 1280 >> 13 sigma.
#define QCAP 1280

// ws layout (floats): [0..1024) partial sums (only use now)
#define SUMS_OFF 0
#define WS_FLOATS 1024
#define WS_NEEDED_BYTES (WS_FLOATS * sizeof(float))

// ---------------------------------------------------------------------------
// Kernel 1: prep. Planes 0..5: per-block partial sums of displacement
// channels. Plane 6: zero d_out (all deposits land there atomically).
// ---------------------------------------------------------------------------
__global__ __launch_bounds__(256) void prep_kernel(const float* __restrict__ x,
                                                   float* __restrict__ ws,
                                                   float* __restrict__ out) {
    const int plane = blockIdx.y;
    if (plane < 6) {
        const int n = plane / 3, c = plane % 3;
        const float4* xp = (const float4*)(x + ((size_t)n * 4 + c) * NP);
        float s = 0.0f;
        for (int i = blockIdx.x * 256 + threadIdx.x; i < NP / 4; i += 128 * 256) {
            float4 v = xp[i];
            s += (v.x + v.y) + (v.z + v.w);
        }
        #pragma unroll
        for (int off = 32; off > 0; off >>= 1) s += __shfl_down(s, off, 64);
        __shared__ float wsum[4];
        if ((threadIdx.x & 63) == 0) wsum[threadIdx.x >> 6] = s;
        __syncthreads();
        if (threadIdx.x == 0)
            ws[SUMS_OFF + plane * 128 + blockIdx.x] =
                (wsum[0] + wsum[1]) + (wsum[2] + wsum[3]);
    } else {
        float4* o4 = (float4*)out;
        const float4 z = make_float4(0.f, 0.f, 0.f, 0.f);
        for (int i = blockIdx.x * 256 + threadIdx.x; i < NBATCH * NP / 4; i += 128 * 256)
            o4[i] = z;
    }
}

// Fallback-path means (serial 128-sum; only used by scatter_direct_kernel).
__device__ __forceinline__ void load_means128(const float* __restrict__ ws, int n,
                                              float& m0, float& m1, float& m2) {
    float s0 = 0.f, s1 = 0.f, s2 = 0.f;
    const float* p0 = ws + SUMS_OFF + (n * 3 + 0) * 128;
    const float* p1 = ws + SUMS_OFF + (n * 3 + 1) * 128;
    const float* p2 = ws + SUMS_OFF + (n * 3 + 2) * 128;
    #pragma unroll 4
    for (int b = 0; b < 128; ++b) { s0 += p0[b]; s1 += p1[b]; s2 += p2[b]; }
    const float inv_np = 1.0f / (float)NP;
    m0 = s0 * inv_np; m1 = s1 * inv_np; m2 = s2 * inv_np;
}

// Packed pair deposit: cells (b, b+1) get (va, vb) in 2^-24 fixed point.
__device__ __forceinline__ void deposit_pair(unsigned long long* __restrict__ winU,
                                             int b, float va, float vb) {
    const int fa = __float2int_rn(va * FXSCALE);
    const int fb = __float2int_rn(vb * FXSCALE);
    const bool odd = (b & 1);
    const long long packed = (((long long)fb) << 32) + (long long)fa;
    const long long hiOnly = ((long long)fa) << 32;
    atomicAdd(&winU[b >> 1], (unsigned long long)(odd ? hiOnly : packed));
    if (odd) atomicAdd(&winU[(b >> 1) + 1], (unsigned long long)(long long)fb);
}

// General-case deposit: window cells -> packed u64 LDS atomics; in-mesh but
// out-of-window -> float global atomics on out (rare: ~2.4% of particles).
__device__ __forceinline__ void slow_deposit(unsigned long long* __restrict__ winU,
                                             float* __restrict__ sp,
                                             float pd, float ph, float pw, float v,
                                             int od, int oh, int ow) {
    const float fd = floorf(pd), fh = floorf(ph), fw = floorf(pw);
    const int id = (int)fd, ih = (int)fh, iw = (int)fw;
    const float rd = pd - fd, rh = ph - fh, rw = pw - fw;
    const int wd = id - od, wh = ih - oh, ww = iw - ow;
    const float wd2[2] = {1.0f - rd, rd};
    const float wh2[2] = {1.0f - rh, rh};
    const float ww2[2] = {1.0f - rw, rw};
    #pragma unroll
    for (int dd = 0; dd < 2; ++dd) {
        const int td = id + dd, wdc = wd + dd;
        const bool dW = (unsigned)wdc < WIN, dM = (unsigned)td < NDIM;
        if (!dM && !dW) continue;
        #pragma unroll
        for (int hh = 0; hh < 2; ++hh) {
            const int th = ih + hh, whc = wh + hh;
            const bool hW = (unsigned)whc < WIN, hM = (unsigned)th < NDIM;
            const float vdh = v * wd2[dd] * wh2[hh];
            #pragma unroll
            for (int wi = 0; wi < 2; ++wi) {
                const int tw = iw + wi, wwc = ww + wi;
                const bool wW = (unsigned)wwc < WIN, wM = (unsigned)tw < NDIM;
                const float dep = vdh * ww2[wi];
                if (dW && hW && wW) {
                    const int cb = (wdc * WIN + whc) * WIN + wwc;
                    const int fx = __float2int_rn(dep * FXSCALE);
                    const long long cv = (cb & 1)
                        ? (((long long)fx) << 32) : (long long)fx;
                    atomicAdd(&winU[cb >> 1], (unsigned long long)cv);
                } else if (dM && hM && wM) {
                    atomicAdd(sp + ((size_t)td * NDIM + th) * NDIM + tw, dep);
                }
            }
        }
    }
}

// ---------------------------------------------------------------------------
// Kernel 2: tiled CIC scatter, direct atomic flush. Deposit (u64 window +
// spill queue, r2/r5-proven) -> drain -> decode -> coalesced global f32
// atomicAdd of the window into out (cell-linear: consecutive lanes hit
// consecutive global x; out-of-mesh cells clipped; zero cells skipped).
// ---------------------------------------------------------------------------
__global__ __launch_bounds__(NTHR, 4) void scatter_tile_kernel(
        const float* __restrict__ x, const float* __restrict__ ws,
        float* __restrict__ out) {
    const int blk = blockIdx.x;              // 0 .. 2*NTILE-1
    const int n = blk >> 9;
    const int t = blk & (NTILE - 1);
    const int tx = t & 7, ty = (t >> 3) & 7, tz = t >> 6;

    __shared__ ulonglong2 win2[(WINF + 3) / 4 + 1];   // 78752 B
    __shared__ float smean[3];
    __shared__ int qcount;
    __shared__ unsigned short queue[QCAP];            // 2560 B
    unsigned long long* winU = (unsigned long long*)win2;
    {
        float4* z4 = (float4*)win2;
        const float4 z = make_float4(0.f, 0.f, 0.f, 0.f);
        for (int i = threadIdx.x; i < (WINF + 3) / 4 + 1; i += NTHR) z4[i] = z;
        if (threadIdx.x == 0) qcount = 0;
    }
    // means: waves 0..2 each reduce one channel's 128 partials (deterministic)
    if (threadIdx.x < 192) {
        const int c = threadIdx.x >> 6;      // 0..2
        const int l = threadIdx.x & 63;
        const float* p = ws + SUMS_OFF + (n * 3 + c) * 128;
        float s = p[l] + p[l + 64];
        #pragma unroll
        for (int off = 32; off > 0; off >>= 1) s += __shfl_down(s, off, 64);
        if (l == 0) smean[c] = s * (1.0f / (float)NP);
    }
    __syncthreads();
    const float m0 = smean[0], m1 = smean[1], m2 = smean[2];

    // ---- deposit phase: 512 threads x 8 particles ----
    const int i0 = threadIdx.x * 8;
    const int lw0 = i0 & 15;
    const int lh  = (i0 >> 4) & 15;
    const int ld  = i0 >> 8;
    const int gd = tz * TS + ld, gh = ty * TS + lh, gw0 = tx * TS + lw0;
    const size_t prow = ((size_t)gd * NDIM + gh) * NDIM + gw0;

    const float4* x4 = (const float4*)(x + (size_t)n * 4 * NP);
    const size_t q = prow >> 2;
    const size_t s4 = NP / 4;
    float4 a0 = x4[0 * s4 + q], a1 = x4[0 * s4 + q + 1];
    float4 b0 = x4[1 * s4 + q], b1 = x4[1 * s4 + q + 1];
    float4 c0 = x4[2 * s4 + q], c1 = x4[2 * s4 + q + 1];
    float4 e0 = x4[3 * s4 + q], e1 = x4[3 * s4 + q + 1];
    const float D0[8] = {a0.x, a0.y, a0.z, a0.w, a1.x, a1.y, a1.z, a1.w};
    const float D1[8] = {b0.x, b0.y, b0.z, b0.w, b1.x, b1.y, b1.z, b1.w};
    const float D2[8] = {c0.x, c0.y, c0.z, c0.w, c1.x, c1.y, c1.z, c1.w};
    const float VV[8] = {e0.x, e0.y, e0.z, e0.w, e1.x, e1.y, e1.z, e1.w};

    const int od = tz * TS - LO, oh = ty * TS - LO, ow = tx * TS - LO;
    float* sp = out + (size_t)n * NP;

    #pragma unroll
    for (int k = 0; k < 8; ++k) {
        const float pd = (D0[k] - m0) * DIS_NORM + (float)gd + 0.5f;
        const float ph = (D1[k] - m1) * DIS_NORM + (float)gh + 0.5f;
        const float pw = (D2[k] - m2) * DIS_NORM + (float)(gw0 + k) + 0.5f;
        const float v = VV[k];

        const float fd = floorf(pd), fh = floorf(ph), fw = floorf(pw);
        const int id = (int)fd, ih = (int)fh, iw = (int)fw;
        const float rd = pd - fd, rh = ph - fh, rw = pw - fw;

        const int wd = id - od, wh = ih - oh, ww = iw - ow;
        if ((unsigned)wd <= WIN - 2 && (unsigned)wh <= WIN - 2 &&
            (unsigned)ww <= WIN - 2) {
            const int b00 = (wd * WIN + wh) * WIN + ww;
            const float sd0 = v * (1.0f - rd), sd1 = v * rd;
            const float h0 = 1.0f - rh, h1 = rh;
            const float q0 = 1.0f - rw, q1 = rw;
            deposit_pair(winU, b00,              sd0 * h0 * q0, sd0 * h0 * q1);
            deposit_pair(winU, b00 + WIN,        sd0 * h1 * q0, sd0 * h1 * q1);
            deposit_pair(winU, b00 + WIN2,       sd1 * h0 * q0, sd1 * h0 * q1);
            deposit_pair(winU, b00 + WIN2 + WIN, sd1 * h1 * q0, sd1 * h1 * q1);
        } else {
            const int qi = atomicAdd(&qcount, 1);
            if (qi < QCAP) {
                queue[qi] = (unsigned short)(i0 + k);
            } else {
                slow_deposit(winU, sp, pd, ph, pw, v, od, oh, ow);
            }
        }
    }

    __syncthreads();

    // ---- drain spill queue: all lanes active, ~98 entries/block ----
    {
        const int nq = min(qcount, QCAP);
        const float* xb = x + (size_t)n * 4 * NP;
        for (int qi = threadIdx.x; qi < nq; qi += NTHR) {
            const int p = queue[qi];
            const int lw = p & 15, lhq = (p >> 4) & 15, ldq = p >> 8;
            const int gdq = tz * TS + ldq, ghq = ty * TS + lhq, gwq = tx * TS + lw;
            const size_t pr = ((size_t)gdq * NDIM + ghq) * NDIM + gwq;
            const float pd = (xb[pr] - m0) * DIS_NORM + (float)gdq + 0.5f;
            const float ph = (xb[(size_t)NP + pr] - m1) * DIS_NORM + (float)ghq + 0.5f;
            const float pw = (xb[2 * (size_t)NP + pr] - m2) * DIS_NORM + (float)gwq + 0.5f;
            const float v = xb[3 * (size_t)NP + pr];
            slow_deposit(winU, sp, pd, ph, pw, v, od, oh, ow);
        }
    }
    __syncthreads();

    // ---- decode pass: in-place u64 fixed-point -> 2x fp32 (no races) ----
    {
        const int NU = (WINF + 1) / 2;   // 9842
        for (int i = threadIdx.x; i < NU; i += NTHR) {
            const unsigned long long u = winU[i];
            const int lo = (int)(unsigned)(u & 0xffffffffull);
            const int hi = (int)(u >> 32) + (lo < 0 ? 1 : 0);
            float2 f;
            f.x = (float)lo * FXINV;
            f.y = (float)hi * FXINV;
            ((float2*)winU)[i] = f;
        }
    }
    __syncthreads();
    const float* winF = (const float*)winU;

    // ---- flush: coalesced global f32 atomics, cell-linear mapping ----
    // Consecutive threads handle consecutive window cells -> consecutive
    // global x within a row (~4-8 cache lines per wave-atomic instr).
    for (int c = threadIdx.x; c < WINF; c += NTHR) {
        const int lz = c / WIN2;
        const int rem = c - lz * WIN2;
        const int ly = rem / WIN;
        const int lx = rem - ly * WIN;
        const int gz = od + lz, gy = oh + ly, gx = ow + lx;
        const float val = winF[c];
        if (((unsigned)gz < NDIM) & ((unsigned)gy < NDIM) &
            ((unsigned)gx < NDIM) & (val != 0.0f)) {
            atomicAdd(sp + ((size_t)gz * NDIM + gy) * NDIM + gx, val);
        }
    }
}

// ---------------------------------------------------------------------------
// Fallback (small ws): direct device-scope atomic scatter into out
// ---------------------------------------------------------------------------
__global__ __launch_bounds__(256) void scatter_direct_kernel(const float* __restrict__ x,
                                                             const float* __restrict__ ws,
                                                             float* __restrict__ out) {
    const int lin = blockIdx.x * 256 + threadIdx.x;
    const int n = lin >> 21;
    const int p = lin & (NP - 1);

    float m0, m1, m2;
    load_means128(ws, n, m0, m1, m2);

    const size_t base = (size_t)n * 4 * NP;
    const float d0 = x[base + 0 * (size_t)NP + p];
    const float d1 = x[base + 1 * (size_t)NP + p];
    const float d2 = x[base + 2 * (size_t)NP + p];
    const float v  = x[base + 3 * (size_t)NP + p];

    const int w = p & 127, h = (p >> 7) & 127, d = p >> 14;
    const float pd = (d0 - m0) * DIS_NORM + (float)d + 0.5f;
    const float ph = (d1 - m1) * DIS_NORM + (float)h + 0.5f;
    const float pw = (d2 - m2) * DIS_NORM + (float)w + 0.5f;
    const float fd = floorf(pd), fh = floorf(ph), fw = floorf(pw);
    const int id = (int)fd, ih = (int)fh, iw = (int)fw;
    const float rd = pd - fd, rh = ph - fh, rw = pw - fw;
    const float wd[2] = {1.0f - rd, rd}, wh[2] = {1.0f - rh, rh}, ww[2] = {1.0f - rw, rw};
    float* o = out + (size_t)n * NP;
    #pragma unroll
    for (int dd = 0; dd < 2; ++dd) {
        const int td = id + dd;
        if ((unsigned)td >= (unsigned)NDIM) continue;
        #pragma unroll
        for (int hh = 0; hh < 2; ++hh) {
            const int th = ih + hh;
            if ((unsigned)th >= (unsigned)NDIM) continue;
            const float vdh = v * wd[dd] * wh[hh];
            const int rowbase = (td * NDIM + th) * NDIM;
            #pragma unroll
            for (int wi = 0; wi < 2; ++wi) {
                const int tw = iw + wi;
                if ((unsigned)tw >= (unsigned)NDIM) continue;
                atomicAdd(o + rowbase + tw, vdh * ww[wi]);
            }
        }
    }
}

extern "C" void kernel_launch(void* const* d_in, const int* in_sizes, int n_in,
                              void* d_out, int out_size, void* d_ws, size_t ws_size,
                              hipStream_t stream) {
    const float* x = (const float*)d_in[0];
    float* out = (float*)d_out;
    float* ws = (float*)d_ws;

    dim3 pgrid(128, 7);   // 6 sum planes + 1 out-zero plane

    if (ws_size >= WS_NEEDED_BYTES) {
        prep_kernel<<<pgrid, 256, 0, stream>>>(x, ws, out);
        scatter_tile_kernel<<<dim3(NBATCH * NTILE), NTHR, 0, stream>>>(x, ws, out);
    } else {
        prep_kernel<<<pgrid, 256, 0, stream>>>(x, ws, out);
        scatter_direct_kernel<<<dim3(NBATCH * NP / 256), 256, 0, stream>>>(x, ws, out);
    }
}

// Round 8
// 186.369 us; speedup vs baseline: 1.1362x; 1.1362x over previous
//
#include <hip/hip_runtime.h>
#include <hip/hip_cooperative_groups.h>

namespace cg = cooperative_groups;

// Problem constants (fixed by reference: x is (2, 4, 128, 128, 128) fp32)
#define NBATCH 2
#define NDIM   128
#define NP     (128 * 128 * 128)        // particles per batch = mesh cells (2^21)
#define DIS_NORM 3.072f                  // 6 * 512 / 1000

// Tiling: 16^3 origin tiles; LDS window halo LO=5 below, HI=6 above.
// WIN=27 -> 19683 cells as PACKED u64 pairs (2 cells/word), 2^-24 fixed point,
// native u64 LDS atomics (fp32 LDS atomicAdd is a CAS loop: 2.7x slower, r3;
// WIN=23 spill blowup: +47us, r4; direct global-atomic flush: +57us, r6).
// r7 cooperative attempt produced all-zero output => launch was rejected
// (162.8KB/CU left no margin for runtime LDS reservation). This round: LDS
// trimmed to ~79.6KB/block, host-side occupancy pre-check, checked launch,
// and the verified r5 3-kernel path as fallback.
#define TS   16
#define LO   5
#define HI   6
#define WIN  (TS + LO + HI)              // 27
#define WIN2 (WIN * WIN)                 // 729
#define WINF (WIN * WIN * WIN)           // 19683
#define TPB  8
#define NTILE (TPB * TPB * TPB)          // 512 tiles per batch
#define NTHR 512
#define NBLK 512                         // co-resident cooperative grid

#define FXSCALE 16777216.0f              // 2^24
#define FXINV   (1.0f / 16777216.0f)

// Spill queues: expected ~98 slow particles/block (2.4% of 4096, sigma~9.8).
#define QCAP_F 384                       // fused kernel (29 sigma + inline fallback)
#define QCAP   1280                      // standalone r5 scatter

// Destination-major inbox: each dest tile owns a contiguous slab of 27
// pieces (source offset o = src - dest; extents by j = 1 - m: {6,16,5}),
// piece bases padded to 4 floats. Slab = 19692 -> 19696 floats.
#define SLAB 19696

// ws layout (floats): [0..1024) partial sums; [1024..) per-tile slabs
#define SUMS_OFF 0
#define SLABS_OFF 1024
#define WS_FLOATS ((size_t)SLABS_OFF + (size_t)NBATCH * NTILE * SLAB)
#define WS_NEEDED_BYTES (WS_FLOATS * sizeof(float))

// Cumulative piece bases for extents e={6,16,5}, each piece padded to x4.
__device__ __constant__ int BASE27[27] = {
    0,216,792,972,1548,3084,3564,3744,4224,
    4376,4952,6488,6968,8504,12600,13880,14360,15640,
    16040,16220,16700,16852,17332,18612,19012,19164,19564};

// Packed pair deposit: cells (b, b+1) get (va, vb) in 2^-24 fixed point.
__device__ __forceinline__ void deposit_pair(unsigned long long* __restrict__ winU,
                                             int b, float va, float vb) {
    const int fa = __float2int_rn(va * FXSCALE);
    const int fb = __float2int_rn(vb * FXSCALE);
    const bool odd = (b & 1);
    const long long packed = (((long long)fb) << 32) + (long long)fa;
    const long long hiOnly = ((long long)fa) << 32;
    atomicAdd(&winU[b >> 1], (unsigned long long)(odd ? hiOnly : packed));
    if (odd) atomicAdd(&winU[(b >> 1) + 1], (unsigned long long)(long long)fb);
}

// General-case deposit: window cells -> packed u64 LDS atomics; in-mesh but
// out-of-window -> float global atomics on out (native on gfx950).
__device__ __forceinline__ void slow_deposit(unsigned long long* __restrict__ winU,
                                             float* __restrict__ sp,
                                             float pd, float ph, float pw, float v,
                                             int od, int oh, int ow) {
    const float fd = floorf(pd), fh = floorf(ph), fw = floorf(pw);
    const int id = (int)fd, ih = (int)fh, iw = (int)fw;
    const float rd = pd - fd, rh = ph - fh, rw = pw - fw;
    const int wd = id - od, wh = ih - oh, ww = iw - ow;
    const float wd2[2] = {1.0f - rd, rd};
    const float wh2[2] = {1.0f - rh, rh};
    const float ww2[2] = {1.0f - rw, rw};
    #pragma unroll
    for (int dd = 0; dd < 2; ++dd) {
        const int td = id + dd, wdc = wd + dd;
        const bool dW = (unsigned)wdc < WIN, dM = (unsigned)td < NDIM;
        if (!dM && !dW) continue;
        #pragma unroll
        for (int hh = 0; hh < 2; ++hh) {
            const int th = ih + hh, whc = wh + hh;
            const bool hW = (unsigned)whc < WIN, hM = (unsigned)th < NDIM;
            const float vdh = v * wd2[dd] * wh2[hh];
            #pragma unroll
            for (int wi = 0; wi < 2; ++wi) {
                const int tw = iw + wi, wwc = ww + wi;
                const bool wW = (unsigned)wwc < WIN, wM = (unsigned)tw < NDIM;
                const float dep = vdh * ww2[wi];
                if (dW && hW && wW) {
                    const int cb = (wdc * WIN + whc) * WIN + wwc;
                    const int fx = __float2int_rn(dep * FXSCALE);
                    const long long cv = (cb & 1)
                        ? (((long long)fx) << 32) : (long long)fx;
                    atomicAdd(&winU[cb >> 1], (unsigned long long)cv);
                } else if (dM && hM && wM) {
                    atomicAdd(sp + ((size_t)td * NDIM + th) * NDIM + tw, dep);
                }
            }
        }
    }
}

// ---------------------------------------------------------------------------
// Fused cooperative kernel: phase0 (zero out + mean partials) -> grid.sync ->
// phase1 (tiled CIC scatter + slab flush, 2 tiles/block) -> grid.sync ->
// phase2 (float4-quad gather, 2 tiles/block). LDS ~79.6KB -> 2 blocks/CU.
// ---------------------------------------------------------------------------
__global__ __launch_bounds__(NTHR, 4) void fused_kernel(const float* __restrict__ x,
                                                        float* __restrict__ ws,
                                                        float* __restrict__ out) {
    cg::grid_group grid = cg::this_grid();
    const int b = blockIdx.x;
    const int tid = threadIdx.x;

    __shared__ ulonglong2 win2[(WINF + 3) / 4 + 1];   // 78752 B
    __shared__ float smean[3];
    __shared__ float wsum8[8];
    __shared__ int qcount;
    __shared__ unsigned short queue[QCAP_F];          // 768 B
    unsigned long long* winU = (unsigned long long*)win2;

    // ================= phase 0: zero out + 6x64 partial sums =================
    {
        float4* o4 = (float4*)out;
        const float4 z = make_float4(0.f, 0.f, 0.f, 0.f);
        for (int i = b * NTHR + tid; i < NBATCH * NP / 4; i += NBLK * NTHR)
            o4[i] = z;
    }
    if (b < 384) {
        const int plane = b >> 6, chunk = b & 63;     // plane = n*3+c
        const float4* xp = (const float4*)(x + ((size_t)(plane / 3) * 4 + plane % 3) * NP);
        float s = 0.0f;
        for (int i = chunk * NTHR + tid; i < NP / 4; i += 64 * NTHR) {
            float4 v = xp[i];
            s += (v.x + v.y) + (v.z + v.w);
        }
        #pragma unroll
        for (int off = 32; off > 0; off >>= 1) s += __shfl_down(s, off, 64);
        if ((tid & 63) == 0) wsum8[tid >> 6] = s;
        __syncthreads();
        if (tid == 0) {
            float t = 0.f;
            #pragma unroll
            for (int w = 0; w < 8; ++w) t += wsum8[w];
            ws[SUMS_OFF + plane * 64 + chunk] = t;
        }
    }
    grid.sync();

    // ================= phase 1: scatter, 2 tiles per block =================
    float* slabs = ws + SLABS_OFF;
    for (int rep = 0; rep < 2; ++rep) {
        const int blk = b + rep * NBLK;              // 0 .. 1023
        const int n = blk >> 9;
        const int t = blk & (NTILE - 1);
        const int tx = t & 7, ty = (t >> 3) & 7, tz = t >> 6;

        __syncthreads();   // previous rep's flush reads of winF complete
        {
            float4* z4 = (float4*)win2;
            const float4 z = make_float4(0.f, 0.f, 0.f, 0.f);
            for (int i = tid; i < (WINF + 3) / 4 + 1; i += NTHR) z4[i] = z;
            if (tid == 0) qcount = 0;
        }
        // means: waves 0..2 each reduce one channel's 64 partials
        if (tid < 192) {
            const int c = tid >> 6;
            const int l = tid & 63;
            float s = ws[SUMS_OFF + (n * 3 + c) * 64 + l];
            #pragma unroll
            for (int off = 32; off > 0; off >>= 1) s += __shfl_down(s, off, 64);
            if (l == 0) smean[c] = s * (1.0f / (float)NP);
        }
        __syncthreads();
        const float m0 = smean[0], m1 = smean[1], m2 = smean[2];

        // ---- deposit phase: 512 threads x 8 particles ----
        const int i0 = tid * 8;
        const int lw0 = i0 & 15;
        const int lh  = (i0 >> 4) & 15;
        const int ld  = i0 >> 8;
        const int gd = tz * TS + ld, gh = ty * TS + lh, gw0 = tx * TS + lw0;
        const size_t prow = ((size_t)gd * NDIM + gh) * NDIM + gw0;

        const float4* x4 = (const float4*)(x + (size_t)n * 4 * NP);
        const size_t q = prow >> 2;
        const size_t s4 = NP / 4;
        float4 a0 = x4[0 * s4 + q], a1 = x4[0 * s4 + q + 1];
        float4 b0 = x4[1 * s4 + q], b1 = x4[1 * s4 + q + 1];
        float4 c0 = x4[2 * s4 + q], c1 = x4[2 * s4 + q + 1];
        float4 e0 = x4[3 * s4 + q], e1 = x4[3 * s4 + q + 1];
        const float D0[8] = {a0.x, a0.y, a0.z, a0.w, a1.x, a1.y, a1.z, a1.w};
        const float D1[8] = {b0.x, b0.y, b0.z, b0.w, b1.x, b1.y, b1.z, b1.w};
        const float D2[8] = {c0.x, c0.y, c0.z, c0.w, c1.x, c1.y, c1.z, c1.w};
        const float VV[8] = {e0.x, e0.y, e0.z, e0.w, e1.x, e1.y, e1.z, e1.w};

        const int od = tz * TS - LO, oh = ty * TS - LO, ow = tx * TS - LO;
        float* sp = out + (size_t)n * NP;

        #pragma unroll
        for (int k = 0; k < 8; ++k) {
            const float pd = (D0[k] - m0) * DIS_NORM + (float)gd + 0.5f;
            const float ph = (D1[k] - m1) * DIS_NORM + (float)gh + 0.5f;
            const float pw = (D2[k] - m2) * DIS_NORM + (float)(gw0 + k) + 0.5f;
            const float v = VV[k];

            const float fd = floorf(pd), fh = floorf(ph), fw = floorf(pw);
            const int id = (int)fd, ih = (int)fh, iw = (int)fw;
            const float rd = pd - fd, rh = ph - fh, rw = pw - fw;

            const int wd = id - od, wh = ih - oh, ww = iw - ow;
            if ((unsigned)wd <= WIN - 2 && (unsigned)wh <= WIN - 2 &&
                (unsigned)ww <= WIN - 2) {
                const int b00 = (wd * WIN + wh) * WIN + ww;
                const float sd0 = v * (1.0f - rd), sd1 = v * rd;
                const float h0 = 1.0f - rh, h1 = rh;
                const float q0 = 1.0f - rw, q1 = rw;
                deposit_pair(winU, b00,              sd0 * h0 * q0, sd0 * h0 * q1);
                deposit_pair(winU, b00 + WIN,        sd0 * h1 * q0, sd0 * h1 * q1);
                deposit_pair(winU, b00 + WIN2,       sd1 * h0 * q0, sd1 * h0 * q1);
                deposit_pair(winU, b00 + WIN2 + WIN, sd1 * h1 * q0, sd1 * h1 * q1);
            } else {
                const int qi = atomicAdd(&qcount, 1);
                if (qi < QCAP_F) queue[qi] = (unsigned short)(i0 + k);
                else slow_deposit(winU, sp, pd, ph, pw, v, od, oh, ow);
            }
        }

        __syncthreads();

        // ---- drain spill queue: all lanes active, ~98 entries/block ----
        {
            const int nq = min(qcount, QCAP_F);
            const float* xb = x + (size_t)n * 4 * NP;
            for (int qi = tid; qi < nq; qi += NTHR) {
                const int p = queue[qi];
                const int lw = p & 15, lhq = (p >> 4) & 15, ldq = p >> 8;
                const int gdq = tz * TS + ldq, ghq = ty * TS + lhq, gwq = tx * TS + lw;
                const size_t pr = ((size_t)gdq * NDIM + ghq) * NDIM + gwq;
                const float pd = (xb[pr] - m0) * DIS_NORM + (float)gdq + 0.5f;
                const float ph = (xb[(size_t)NP + pr] - m1) * DIS_NORM + (float)ghq + 0.5f;
                const float pw = (xb[2 * (size_t)NP + pr] - m2) * DIS_NORM + (float)gwq + 0.5f;
                const float v = xb[3 * (size_t)NP + pr];
                slow_deposit(winU, sp, pd, ph, pw, v, od, oh, ow);
            }
        }
        __syncthreads();

        // ---- decode pass: in-place u64 fixed-point -> 2x fp32 ----
        {
            const int NU = (WINF + 1) / 2;   // 9842
            for (int i = tid; i < NU; i += NTHR) {
                const unsigned long long u = winU[i];
                const int lo = (int)(unsigned)(u & 0xffffffffull);
                const int hi = (int)(u >> 32) + (lo < 0 ? 1 : 0);
                float2 f;
                f.x = (float)lo * FXINV;
                f.y = (float)hi * FXINV;
                ((float2*)winU)[i] = f;
            }
        }
        __syncthreads();
        const float* winF = (const float*)winU;

        // ---- flush: one thread per (lz,ly) row; 3 fixed x-segments ----
        const int EXTY[3] = {6, 16, 5};
        const int nbase = n << 9;
        for (int r = tid; r < WIN2; r += NTHR) {
            const int lz = r / WIN;
            const int ly = r - lz * WIN;
            int mz, pz;
            if (lz < LO) { mz = -1; pz = lz; }
            else if (lz < LO + TS) { mz = 0; pz = lz - LO; }
            else { mz = 1; pz = lz - LO - TS; }
            int my, py;
            if (ly < LO) { my = -1; py = ly; }
            else if (ly < LO + TS) { my = 0; py = ly - LO; }
            else { my = 1; py = ly - LO - TS; }
            const int dtz = tz + mz, dty = ty + my;
            if ((unsigned)dtz >= TPB || (unsigned)dty >= TPB) continue;

            const int jz = 1 - mz, jy = 1 - my;
            const int ey = EXTY[jy];
            const int rowoff = pz * ey + py;
            const int pobase = jz * 9 + jy * 3;
            const float* src = winF + r * WIN;
            const int slabRow = nbase + (dtz * 8 + dty) * 8;

            if (tx > 0) {                      // seg A: jx=2, lx 0..4, ex=5
                float* d = slabs + (size_t)(slabRow + tx - 1) * SLAB
                         + BASE27[pobase + 2] + rowoff * 5;
                #pragma unroll
                for (int k = 0; k < 5; ++k) d[k] = src[k];
            }
            {                                  // seg B: jx=1, lx 5..20, ex=16
                float* d = slabs + (size_t)(slabRow + tx) * SLAB
                         + BASE27[pobase + 1] + rowoff * 16;
                #pragma unroll
                for (int k = 0; k < 4; ++k) {
                    float4 v;
                    v.x = src[5 + 4 * k]; v.y = src[6 + 4 * k];
                    v.z = src[7 + 4 * k]; v.w = src[8 + 4 * k];
                    ((float4*)d)[k] = v;
                }
            }
            if (tx < TPB - 1) {                // seg C: jx=0, lx 21..26, ex=6
                float* d = slabs + (size_t)(slabRow + tx + 1) * SLAB
                         + BASE27[pobase + 0] + rowoff * 6;
                #pragma unroll
                for (int k = 0; k < 6; ++k) d[k] = src[21 + k];
            }
        }
    }
    grid.sync();

    // ================= phase 2: gather, 2 tiles per block =================
    for (int rep = 0; rep < 2; ++rep) {
        const int blk = b + rep * NBLK;
        const int n = blk >> 9;
        const int t = blk & (NTILE - 1);
        const int tx = t & 7, ty = (t >> 3) & 7, tz = t >> 6;

        const float* __restrict__ slab = slabs + (size_t)blk * SLAB;
        const float4* __restrict__ slab4 = (const float4*)slab;
        float4* __restrict__ o4 = (float4*)(out + (size_t)n * NP);

        for (int i4 = tid; i4 < TS * TS * TS / 4; i4 += NTHR) {
            const int xq = i4 & 3, y = (i4 >> 2) & 15, z = i4 >> 6;

            int ysec = 0, yp = 0, ye = 0; bool y2 = false;
            if (y < 6)        { if (ty > 0)       { ysec = 0; yp = y;      ye = 6; y2 = true; } }
            else if (y >= 11) { if (ty < TPB - 1) { ysec = 6; yp = y - 11; ye = 5; y2 = true; } }
            int zsec = 0, zp = 0; bool z2 = false;
            if (z < 6)        { if (tz > 0)       { zsec = 0;  zp = z;      z2 = true; } }
            else if (z >= 11) { if (tz < TPB - 1) { zsec = 18; zp = z - 11; z2 = true; } }

            const int rC = z * 16 + y;
            float4 s = slab4[(BASE27[13] >> 2) + rC * 4 + xq];
            int rY = 0, rZ = 0, rYZ = 0;
            if (y2) {
                rY = z * ye + yp;
                const float4 v = slab4[(BASE27[10 + ysec] >> 2) + rY * 4 + xq];
                s.x += v.x; s.y += v.y; s.z += v.z; s.w += v.w;
            }
            if (z2) {
                rZ = zp * 16 + y;
                const float4 v = slab4[(BASE27[zsec + 4] >> 2) + rZ * 4 + xq];
                s.x += v.x; s.y += v.y; s.z += v.z; s.w += v.w;
                if (y2) {
                    rYZ = zp * ye + yp;
                    const float4 v2 = slab4[(BASE27[zsec + ysec + 1] >> 2) + rYZ * 4 + xq];
                    s.x += v2.x; s.y += v2.y; s.z += v2.z; s.w += v2.w;
                }
            }

            float se[4] = {s.x, s.y, s.z, s.w};
            #pragma unroll
            for (int e = 0; e < 4; ++e) {
                const int xx = xq * 4 + e;
                int xsec = 0, xp = 0, xe = 0; bool x2 = false;
                if (xx < 6)        { if (tx > 0)       { xsec = 0; xp = xx;      xe = 6; x2 = true; } }
                else if (xx >= 11) { if (tx < TPB - 1) { xsec = 2; xp = xx - 11; xe = 5; x2 = true; } }
                if (x2) {
                    se[e] += slab[BASE27[12 + xsec] + rC * xe + xp];
                    if (y2) se[e] += slab[BASE27[9 + ysec + xsec] + rY * xe + xp];
                    if (z2) {
                        se[e] += slab[BASE27[zsec + 3 + xsec] + rZ * xe + xp];
                        if (y2) se[e] += slab[BASE27[zsec + ysec + xsec] + rYZ * xe + xp];
                    }
                }
            }

            const size_t grow = ((size_t)(tz * TS + z) * NDIM + ty * TS + y) * (NDIM / 4)
                              + tx * 4 + xq;
            float4 o = o4[grow];
            o.x += se[0]; o.y += se[1]; o.z += se[2]; o.w += se[3];
            o4[grow] = o;
        }
    }
}

// ---------------------------------------------------------------------------
// r5-verified fallback path: prep + scatter_tile + gather_tile (186.6 us).
// ---------------------------------------------------------------------------
__global__ __launch_bounds__(256) void prep_kernel(const float* __restrict__ x,
                                                   float* __restrict__ ws,
                                                   float* __restrict__ out) {
    const int plane = blockIdx.y;
    if (plane < 6) {
        const int n = plane / 3, c = plane % 3;
        const float4* xp = (const float4*)(x + ((size_t)n * 4 + c) * NP);
        float s = 0.0f;
        for (int i = blockIdx.x * 256 + threadIdx.x; i < NP / 4; i += 128 * 256) {
            float4 v = xp[i];
            s += (v.x + v.y) + (v.z + v.w);
        }
        #pragma unroll
        for (int off = 32; off > 0; off >>= 1) s += __shfl_down(s, off, 64);
        __shared__ float wsum[4];
        if ((threadIdx.x & 63) == 0) wsum[threadIdx.x >> 6] = s;
        __syncthreads();
        if (threadIdx.x == 0)
            ws[SUMS_OFF + plane * 128 + blockIdx.x] =
                (wsum[0] + wsum[1]) + (wsum[2] + wsum[3]);
    } else {
        float4* o4 = (float4*)out;
        const float4 z = make_float4(0.f, 0.f, 0.f, 0.f);
        for (int i = blockIdx.x * 256 + threadIdx.x; i < NBATCH * NP / 4; i += 128 * 256)
            o4[i] = z;
    }
}

__device__ __forceinline__ void load_means128(const float* __restrict__ ws, int n,
                                              float& m0, float& m1, float& m2) {
    float s0 = 0.f, s1 = 0.f, s2 = 0.f;
    const float* p0 = ws + SUMS_OFF + (n * 3 + 0) * 128;
    const float* p1 = ws + SUMS_OFF + (n * 3 + 1) * 128;
    const float* p2 = ws + SUMS_OFF + (n * 3 + 2) * 128;
    #pragma unroll 4
    for (int b = 0; b < 128; ++b) { s0 += p0[b]; s1 += p1[b]; s2 += p2[b]; }
    const float inv_np = 1.0f / (float)NP;
    m0 = s0 * inv_np; m1 = s1 * inv_np; m2 = s2 * inv_np;
}

__global__ __launch_bounds__(NTHR, 4) void scatter_tile_kernel(
        const float* __restrict__ x, const float* __restrict__ ws,
        float* __restrict__ slabs, float* __restrict__ out) {
    const int blk = blockIdx.x;              // 0 .. 2*NTILE-1
    const int n = blk >> 9;
    const int t = blk & (NTILE - 1);
    const int tx = t & 7, ty = (t >> 3) & 7, tz = t >> 6;

    __shared__ ulonglong2 win2[(WINF + 3) / 4 + 1];   // 78752 B
    __shared__ float smean[3];
    __shared__ int qcount;
    __shared__ unsigned short queue[QCAP];            // 2560 B
    unsigned long long* winU = (unsigned long long*)win2;
    {
        float4* z4 = (float4*)win2;
        const float4 z = make_float4(0.f, 0.f, 0.f, 0.f);
        for (int i = threadIdx.x; i < (WINF + 3) / 4 + 1; i += NTHR) z4[i] = z;
        if (threadIdx.x == 0) qcount = 0;
    }
    if (threadIdx.x < 192) {
        const int c = threadIdx.x >> 6;
        const int l = threadIdx.x & 63;
        const float* p = ws + SUMS_OFF + (n * 3 + c) * 128;
        float s = p[l] + p[l + 64];
        #pragma unroll
        for (int off = 32; off > 0; off >>= 1) s += __shfl_down(s, off, 64);
        if (l == 0) smean[c] = s * (1.0f / (float)NP);
    }
    __syncthreads();
    const float m0 = smean[0], m1 = smean[1], m2 = smean[2];

    const int i0 = threadIdx.x * 8;
    const int lw0 = i0 & 15;
    const int lh  = (i0 >> 4) & 15;
    const int ld  = i0 >> 8;
    const int gd = tz * TS + ld, gh = ty * TS + lh, gw0 = tx * TS + lw0;
    const size_t prow = ((size_t)gd * NDIM + gh) * NDIM + gw0;

    const float4* x4 = (const float4*)(x + (size_t)n * 4 * NP);
    const size_t q = prow >> 2;
    const size_t s4 = NP / 4;
    float4 a0 = x4[0 * s4 + q], a1 = x4[0 * s4 + q + 1];
    float4 b0 = x4[1 * s4 + q], b1 = x4[1 * s4 + q + 1];
    float4 c0 = x4[2 * s4 + q], c1 = x4[2 * s4 + q + 1];
    float4 e0 = x4[3 * s4 + q], e1 = x4[3 * s4 + q + 1];
    const float D0[8] = {a0.x, a0.y, a0.z, a0.w, a1.x, a1.y, a1.z, a1.w};
    const float D1[8] = {b0.x, b0.y, b0.z, b0.w, b1.x, b1.y, b1.z, b1.w};
    const float D2[8] = {c0.x, c0.y, c0.z, c0.w, c1.x, c1.y, c1.z, c1.w};
    const float VV[8] = {e0.x, e0.y, e0.z, e0.w, e1.x, e1.y, e1.z, e1.w};

    const int od = tz * TS - LO, oh = ty * TS - LO, ow = tx * TS - LO;
    float* sp = out + (size_t)n * NP;

    #pragma unroll
    for (int k = 0; k < 8; ++k) {
        const float pd = (D0[k] - m0) * DIS_NORM + (float)gd + 0.5f;
        const float ph = (D1[k] - m1) * DIS_NORM + (float)gh + 0.5f;
        const float pw = (D2[k] - m2) * DIS_NORM + (float)(gw0 + k) + 0.5f;
        const float v = VV[k];

        const float fd = floorf(pd), fh = floorf(ph), fw = floorf(pw);
        const int id = (int)fd, ih = (int)fh, iw = (int)fw;
        const float rd = pd - fd, rh = ph - fh, rw = pw - fw;

        const int wd = id - od, wh = ih - oh, ww = iw - ow;
        if ((unsigned)wd <= WIN - 2 && (unsigned)wh <= WIN - 2 &&
            (unsigned)ww <= WIN - 2) {
            const int b00 = (wd * WIN + wh) * WIN + ww;
            const float sd0 = v * (1.0f - rd), sd1 = v * rd;
            const float h0 = 1.0f - rh, h1 = rh;
            const float q0 = 1.0f - rw, q1 = rw;
            deposit_pair(winU, b00,              sd0 * h0 * q0, sd0 * h0 * q1);
            deposit_pair(winU, b00 + WIN,        sd0 * h1 * q0, sd0 * h1 * q1);
            deposit_pair(winU, b00 + WIN2,       sd1 * h0 * q0, sd1 * h0 * q1);
            deposit_pair(winU, b00 + WIN2 + WIN, sd1 * h1 * q0, sd1 * h1 * q1);
        } else {
            const int qi = atomicAdd(&qcount, 1);
            if (qi < QCAP) queue[qi] = (unsigned short)(i0 + k);
            else slow_deposit(winU, sp, pd, ph, pw, v, od, oh, ow);
        }
    }

    __syncthreads();

    {
        const int nq = min(qcount, QCAP);
        const float* xb = x + (size_t)n * 4 * NP;
        for (int qi = threadIdx.x; qi < nq; qi += NTHR) {
            const int p = queue[qi];
            const int lw = p & 15, lhq = (p >> 4) & 15, ldq = p >> 8;
            const int gdq = tz * TS + ldq, ghq = ty * TS + lhq, gwq = tx * TS + lw;
            const size_t pr = ((size_t)gdq * NDIM + ghq) * NDIM + gwq;
            const float pd = (xb[pr] - m0) * DIS_NORM + (float)gdq + 0.5f;
            const float ph = (xb[(size_t)NP + pr] - m1) * DIS_NORM + (float)ghq + 0.5f;
            const float pw = (xb[2 * (size_t)NP + pr] - m2) * DIS_NORM + (float)gwq + 0.5f;
            const float v = xb[3 * (size_t)NP + pr];
            slow_deposit(winU, sp, pd, ph, pw, v, od, oh, ow);
        }
    }
    __syncthreads();

    {
        const int NU = (WINF + 1) / 2;   // 9842
        for (int i = threadIdx.x; i < NU; i += NTHR) {
            const unsigned long long u = winU[i];
            const int lo = (int)(unsigned)(u & 0xffffffffull);
            const int hi = (int)(u >> 32) + (lo < 0 ? 1 : 0);
            float2 f;
            f.x = (float)lo * FXINV;
            f.y = (float)hi * FXINV;
            ((float2*)winU)[i] = f;
        }
    }
    __syncthreads();
    const float* winF = (const float*)winU;

    const int EXTY[3] = {6, 16, 5};
    const int nbase = n << 9;
    for (int r = threadIdx.x; r < WIN2; r += NTHR) {
        const int lz = r / WIN;
        const int ly = r - lz * WIN;
        int mz, pz;
        if (lz < LO) { mz = -1; pz = lz; }
        else if (lz < LO + TS) { mz = 0; pz = lz - LO; }
        else { mz = 1; pz = lz - LO - TS; }
        int my, py;
        if (ly < LO) { my = -1; py = ly; }
        else if (ly < LO + TS) { my = 0; py = ly - LO; }
        else { my = 1; py = ly - LO - TS; }
        const int dtz = tz + mz, dty = ty + my;
        if ((unsigned)dtz >= TPB || (unsigned)dty >= TPB) continue;

        const int jz = 1 - mz, jy = 1 - my;
        const int ey = EXTY[jy];
        const int rowoff = pz * ey + py;
        const int pobase = jz * 9 + jy * 3;
        const float* src = winF + r * WIN;
        const int slabRow = nbase + (dtz * 8 + dty) * 8;

        if (tx > 0) {
            float* d = slabs + (size_t)(slabRow + tx - 1) * SLAB
                     + BASE27[pobase + 2] + rowoff * 5;
            #pragma unroll
            for (int k = 0; k < 5; ++k) d[k] = src[k];
        }
        {
            float* d = slabs + (size_t)(slabRow + tx) * SLAB
                     + BASE27[pobase + 1] + rowoff * 16;
            #pragma unroll
            for (int k = 0; k < 4; ++k) {
                float4 v;
                v.x = src[5 + 4 * k]; v.y = src[6 + 4 * k];
                v.z = src[7 + 4 * k]; v.w = src[8 + 4 * k];
                ((float4*)d)[k] = v;
            }
        }
        if (tx < TPB - 1) {
            float* d = slabs + (size_t)(slabRow + tx + 1) * SLAB
                     + BASE27[pobase + 0] + rowoff * 6;
            #pragma unroll
            for (int k = 0; k < 6; ++k) d[k] = src[21 + k];
        }
    }
}

__global__ __launch_bounds__(NTHR) void gather_tile_kernel(const float* __restrict__ slabs,
                                                           float* __restrict__ out) {
    const int blk = blockIdx.x;              // 0 .. 2*NTILE-1
    const int n = blk >> 9;
    const int t = blk & (NTILE - 1);
    const int tx = t & 7, ty = (t >> 3) & 7, tz = t >> 6;

    const float* __restrict__ slab = slabs + (size_t)blk * SLAB;
    const float4* __restrict__ slab4 = (const float4*)slab;
    float4* __restrict__ o4 = (float4*)(out + (size_t)n * NP);

    for (int i4 = threadIdx.x; i4 < TS * TS * TS / 4; i4 += NTHR) {
        const int xq = i4 & 3, y = (i4 >> 2) & 15, z = i4 >> 6;

        int ysec = 0, yp = 0, ye = 0; bool y2 = false;
        if (y < 6)        { if (ty > 0)       { ysec = 0; yp = y;      ye = 6; y2 = true; } }
        else if (y >= 11) { if (ty < TPB - 1) { ysec = 6; yp = y - 11; ye = 5; y2 = true; } }
        int zsec = 0, zp = 0; bool z2 = false;
        if (z < 6)        { if (tz > 0)       { zsec = 0;  zp = z;      z2 = true; } }
        else if (z >= 11) { if (tz < TPB - 1) { zsec = 18; zp = z - 11; z2 = true; } }

        const int rC = z * 16 + y;
        float4 s = slab4[(BASE27[13] >> 2) + rC * 4 + xq];
        int rY = 0, rZ = 0, rYZ = 0;
        if (y2) {
            rY = z * ye + yp;
            const float4 v = slab4[(BASE27[10 + ysec] >> 2) + rY * 4 + xq];
            s.x += v.x; s.y += v.y; s.z += v.z; s.w += v.w;
        }
        if (z2) {
            rZ = zp * 16 + y;
            const float4 v = slab4[(BASE27[zsec + 4] >> 2) + rZ * 4 + xq];
            s.x += v.x; s.y += v.y; s.z += v.z; s.w += v.w;
            if (y2) {
                rYZ = zp * ye + yp;
                const float4 v2 = slab4[(BASE27[zsec + ysec + 1] >> 2) + rYZ * 4 + xq];
                s.x += v2.x; s.y += v2.y; s.z += v2.z; s.w += v2.w;
            }
        }

        float se[4] = {s.x, s.y, s.z, s.w};
        #pragma unroll
        for (int e = 0; e < 4; ++e) {
            const int xx = xq * 4 + e;
            int xsec = 0, xp = 0, xe = 0; bool x2 = false;
            if (xx < 6)        { if (tx > 0)       { xsec = 0; xp = xx;      xe = 6; x2 = true; } }
            else if (xx >= 11) { if (tx < TPB - 1) { xsec = 2; xp = xx - 11; xe = 5; x2 = true; } }
            if (x2) {
                se[e] += slab[BASE27[12 + xsec] + rC * xe + xp];
                if (y2) se[e] += slab[BASE27[9 + ysec + xsec] + rY * xe + xp];
                if (z2) {
                    se[e] += slab[BASE27[zsec + 3 + xsec] + rZ * xe + xp];
                    if (y2) se[e] += slab[BASE27[zsec + ysec + xsec] + rYZ * xe + xp];
                }
            }
        }

        const size_t grow = ((size_t)(tz * TS + z) * NDIM + ty * TS + y) * (NDIM / 4)
                          + tx * 4 + xq;
        float4 o = o4[grow];
        o.x += se[0]; o.y += se[1]; o.z += se[2]; o.w += se[3];
        o4[grow] = o;
    }
}

__global__ __launch_bounds__(256) void scatter_direct_kernel(const float* __restrict__ x,
                                                             const float* __restrict__ ws,
                                                             float* __restrict__ out) {
    const int lin = blockIdx.x * 256 + threadIdx.x;
    const int n = lin >> 21;
    const int p = lin & (NP - 1);

    float m0, m1, m2;
    load_means128(ws, n, m0, m1, m2);

    const size_t base = (size_t)n * 4 * NP;
    const float d0 = x[base + 0 * (size_t)NP + p];
    const float d1 = x[base + 1 * (size_t)NP + p];
    const float d2 = x[base + 2 * (size_t)NP + p];
    const float v  = x[base + 3 * (size_t)NP + p];

    const int w = p & 127, h = (p >> 7) & 127, d = p >> 14;
    const float pd = (d0 - m0) * DIS_NORM + (float)d + 0.5f;
    const float ph = (d1 - m1) * DIS_NORM + (float)h + 0.5f;
    const float pw = (d2 - m2) * DIS_NORM + (float)w + 0.5f;
    const float fd = floorf(pd), fh = floorf(ph), fw = floorf(pw);
    const int id = (int)fd, ih = (int)fh, iw = (int)fw;
    const float rd = pd - fd, rh = ph - fh, rw = pw - fw;
    const float wd[2] = {1.0f - rd, rd}, wh[2] = {1.0f - rh, rh}, ww[2] = {1.0f - rw, rw};
    float* o = out + (size_t)n * NP;
    #pragma unroll
    for (int dd = 0; dd < 2; ++dd) {
        const int td = id + dd;
        if ((unsigned)td >= (unsigned)NDIM) continue;
        #pragma unroll
        for (int hh = 0; hh < 2; ++hh) {
            const int th = ih + hh;
            if ((unsigned)th >= (unsigned)NDIM) continue;
            const float vdh = v * wd[dd] * wh[hh];
            const int rowbase = (td * NDIM + th) * NDIM;
            #pragma unroll
            for (int wi = 0; wi < 2; ++wi) {
                const int tw = iw + wi;
                if ((unsigned)tw >= (unsigned)NDIM) continue;
                atomicAdd(o + rowbase + tw, vdh * ww[wi]);
            }
        }
    }
}

// Cached cooperative-launch feasibility (attribute + occupancy pre-check).
static int g_coop_state = -1;   // -1 unknown, 0 no, 1 yes

extern "C" void kernel_launch(void* const* d_in, const int* in_sizes, int n_in,
                              void* d_out, int out_size, void* d_ws, size_t ws_size,
                              hipStream_t stream) {
    const float* x = (const float*)d_in[0];
    float* out = (float*)d_out;
    float* ws = (float*)d_ws;
    float* slabs = ws + SLABS_OFF;

    if (g_coop_state < 0) {
        int dev = 0;
        (void)hipGetDevice(&dev);
        int coop = 0;
        (void)hipDeviceGetAttribute(&coop, hipDeviceAttributeCooperativeLaunch, dev);
        int occ = 0;
        hipError_t oe = hipOccupancyMaxActiveBlocksPerMultiprocessor(
            &occ, (const void*)fused_kernel, NTHR, 0);
        g_coop_state = (coop != 0 && oe == hipSuccess && occ >= 2) ? 1 : 0;
    }

    if (ws_size >= WS_NEEDED_BYTES && g_coop_state == 1) {
        void* args[] = {(void*)&x, (void*)&ws, (void*)&out};
        hipError_t err = hipLaunchCooperativeKernel((const void*)fused_kernel,
                                                    dim3(NBLK), dim3(NTHR),
                                                    args, 0, stream);
        if (err == hipSuccess) return;
        g_coop_state = 0;   // don't retry; fall through to verified path
    }

    if (ws_size >= WS_NEEDED_BYTES) {
        dim3 pgrid(128, 7);   // 6 sum planes + 1 out-zero plane
        prep_kernel<<<pgrid, 256, 0, stream>>>(x, ws, out);
        scatter_tile_kernel<<<dim3(NBATCH * NTILE), NTHR, 0, stream>>>(x, ws, slabs, out);
        gather_tile_kernel<<<dim3(NBATCH * NTILE), NTHR, 0, stream>>>(slabs, out);
    } else {
        dim3 pgrid(128, 7);
        prep_kernel<<<pgrid, 256, 0, stream>>>(x, ws, out);
        scatter_direct_kernel<<<dim3(NBATCH * NP / 256), 256, 0, stream>>>(x, ws, out);
    }
}

// Round 9
// 176.077 us; speedup vs baseline: 1.2026x; 1.0585x over previous
//
#include <hip/hip_runtime.h>
#include <hip/hip_fp16.h>

// Problem constants (fixed by reference: x is (2, 4, 128, 128, 128) fp32)
#define NBATCH 2
#define NDIM   128
#define NP     (128 * 128 * 128)        // particles per batch = mesh cells (2^21)
#define DIS_NORM 3.072f                  // 6 * 512 / 1000

// Tiling: 16^3 origin tiles; LDS window halo LO=5 below, HI=6 above.
// WIN=27 -> 19683 cells as PACKED u64 pairs (2 cells/word), 2^-24 fixed point,
// native u64 LDS atomics. Measured design decisions:
//  - fp32 LDS atomicAdd is a CAS loop: 2.7x slower (r3)
//  - WIN=23 (3 blocks/CU) spill blowup: +47us (r4)
//  - direct global-atomic window flush: +57us (r6)
//  - cooperative prep/scatter/gather fusion: 272us vs 186 (r8) -- fusion pins
//    all phases at scatter's 2-blocks/CU occupancy; streaming phases lose
//    half their bandwidth. 3-kernel structure is the optimum.
// This round: slabs in fp16 (intermediate-only data; halves scatter's slab
// write and gather's slab read, ~80MB HBM total saved; adds ~0.01 abs error
// vs 0.10 threshold).
#define TS   16
#define LO   5
#define HI   6
#define WIN  (TS + LO + HI)              // 27
#define WIN2 (WIN * WIN)                 // 729
#define WINF (WIN * WIN * WIN)           // 19683
#define TPB  8
#define NTILE (TPB * TPB * TPB)          // 512 tiles per batch
#define NTHR 512

#define FXSCALE 16777216.0f              // 2^24
#define FXINV   (1.0f / 16777216.0f)

// Spill queue: expected ~98 slow particles/block (2.4% of 4096); 1280 >> 13 sigma.
#define QCAP 1280

// Destination-major inbox in fp16: each dest tile owns a contiguous slab of
// 27 pieces (extents by j = 1 - m: {6,16,5}), piece bases padded to 8 halves
// (16B) so ext-16 rows are uint4-addressable. Slab = 19704 halves (39408 B).
#define SLABH 19704

// ws layout (floats): [0..1024) partial sums; [1024..) per-tile fp16 slabs
#define SUMS_OFF 0
#define SLABS_OFF 1024
#define WS_FLOATS ((size_t)SLABS_OFF + (size_t)NBATCH * NTILE * SLABH / 2)
#define WS_NEEDED_BYTES (WS_FLOATS * sizeof(float))

// Cumulative piece bases (in HALVES) for extents e={6,16,5}, pad-to-8.
__device__ __constant__ int BASE27[27] = {
    0,216,792,976,1552,3088,3568,3752,4232,
    4384,4960,6496,6976,8512,12608,13888,14368,15648,
    16048,16232,16712,16864,17344,18624,19024,19176,19576};

// ---------------------------------------------------------------------------
// Kernel 1: prep. Planes 0..5: per-block partial sums of displacement
// channels. Plane 6: zero d_out (float spill deposits land there atomically).
// ---------------------------------------------------------------------------
__global__ __launch_bounds__(256) void prep_kernel(const float* __restrict__ x,
                                                   float* __restrict__ ws,
                                                   float* __restrict__ out) {
    const int plane = blockIdx.y;
    if (plane < 6) {
        const int n = plane / 3, c = plane % 3;
        const float4* xp = (const float4*)(x + ((size_t)n * 4 + c) * NP);
        float s = 0.0f;
        for (int i = blockIdx.x * 256 + threadIdx.x; i < NP / 4; i += 128 * 256) {
            float4 v = xp[i];
            s += (v.x + v.y) + (v.z + v.w);
        }
        #pragma unroll
        for (int off = 32; off > 0; off >>= 1) s += __shfl_down(s, off, 64);
        __shared__ float wsum[4];
        if ((threadIdx.x & 63) == 0) wsum[threadIdx.x >> 6] = s;
        __syncthreads();
        if (threadIdx.x == 0)
            ws[SUMS_OFF + plane * 128 + blockIdx.x] =
                (wsum[0] + wsum[1]) + (wsum[2] + wsum[3]);
    } else {
        float4* o4 = (float4*)out;
        const float4 z = make_float4(0.f, 0.f, 0.f, 0.f);
        for (int i = blockIdx.x * 256 + threadIdx.x; i < NBATCH * NP / 4; i += 128 * 256)
            o4[i] = z;
    }
}

// Fallback-path means (serial 128-sum; only used by scatter_direct_kernel).
__device__ __forceinline__ void load_means128(const float* __restrict__ ws, int n,
                                              float& m0, float& m1, float& m2) {
    float s0 = 0.f, s1 = 0.f, s2 = 0.f;
    const float* p0 = ws + SUMS_OFF + (n * 3 + 0) * 128;
    const float* p1 = ws + SUMS_OFF + (n * 3 + 1) * 128;
    const float* p2 = ws + SUMS_OFF + (n * 3 + 2) * 128;
    #pragma unroll 4
    for (int b = 0; b < 128; ++b) { s0 += p0[b]; s1 += p1[b]; s2 += p2[b]; }
    const float inv_np = 1.0f / (float)NP;
    m0 = s0 * inv_np; m1 = s1 * inv_np; m2 = s2 * inv_np;
}

// Packed pair deposit: cells (b, b+1) get (va, vb) in 2^-24 fixed point.
__device__ __forceinline__ void deposit_pair(unsigned long long* __restrict__ winU,
                                             int b, float va, float vb) {
    const int fa = __float2int_rn(va * FXSCALE);
    const int fb = __float2int_rn(vb * FXSCALE);
    const bool odd = (b & 1);
    const long long packed = (((long long)fb) << 32) + (long long)fa;
    const long long hiOnly = ((long long)fa) << 32;
    atomicAdd(&winU[b >> 1], (unsigned long long)(odd ? hiOnly : packed));
    if (odd) atomicAdd(&winU[(b >> 1) + 1], (unsigned long long)(long long)fb);
}

// General-case deposit: window cells -> packed u64 LDS atomics; in-mesh but
// out-of-window -> float global atomics on out (native on gfx950).
__device__ __forceinline__ void slow_deposit(unsigned long long* __restrict__ winU,
                                             float* __restrict__ sp,
                                             float pd, float ph, float pw, float v,
                                             int od, int oh, int ow) {
    const float fd = floorf(pd), fh = floorf(ph), fw = floorf(pw);
    const int id = (int)fd, ih = (int)fh, iw = (int)fw;
    const float rd = pd - fd, rh = ph - fh, rw = pw - fw;
    const int wd = id - od, wh = ih - oh, ww = iw - ow;
    const float wd2[2] = {1.0f - rd, rd};
    const float wh2[2] = {1.0f - rh, rh};
    const float ww2[2] = {1.0f - rw, rw};
    #pragma unroll
    for (int dd = 0; dd < 2; ++dd) {
        const int td = id + dd, wdc = wd + dd;
        const bool dW = (unsigned)wdc < WIN, dM = (unsigned)td < NDIM;
        if (!dM && !dW) continue;
        #pragma unroll
        for (int hh = 0; hh < 2; ++hh) {
            const int th = ih + hh, whc = wh + hh;
            const bool hW = (unsigned)whc < WIN, hM = (unsigned)th < NDIM;
            const float vdh = v * wd2[dd] * wh2[hh];
            #pragma unroll
            for (int wi = 0; wi < 2; ++wi) {
                const int tw = iw + wi, wwc = ww + wi;
                const bool wW = (unsigned)wwc < WIN, wM = (unsigned)tw < NDIM;
                const float dep = vdh * ww2[wi];
                if (dW && hW && wW) {
                    const int cb = (wdc * WIN + whc) * WIN + wwc;
                    const int fx = __float2int_rn(dep * FXSCALE);
                    const long long cv = (cb & 1)
                        ? (((long long)fx) << 32) : (long long)fx;
                    atomicAdd(&winU[cb >> 1], (unsigned long long)cv);
                } else if (dM && hM && wM) {
                    atomicAdd(sp + ((size_t)td * NDIM + th) * NDIM + tw, dep);
                }
            }
        }
    }
}

// ---------------------------------------------------------------------------
// Kernel 2: tiled CIC scatter + destination-major fp16 flush (r5-proven
// structure: WIN=27, u64 window, spill queue, shuffle means).
// ---------------------------------------------------------------------------
__global__ __launch_bounds__(NTHR, 4) void scatter_tile_kernel(
        const float* __restrict__ x, const float* __restrict__ ws,
        __half* __restrict__ slabs, float* __restrict__ out) {
    const int blk = blockIdx.x;              // 0 .. 2*NTILE-1
    const int n = blk >> 9;
    const int t = blk & (NTILE - 1);
    const int tx = t & 7, ty = (t >> 3) & 7, tz = t >> 6;

    __shared__ ulonglong2 win2[(WINF + 3) / 4 + 1];   // 78752 B
    __shared__ float smean[3];
    __shared__ int qcount;
    __shared__ unsigned short queue[QCAP];            // 2560 B
    unsigned long long* winU = (unsigned long long*)win2;
    {
        float4* z4 = (float4*)win2;
        const float4 z = make_float4(0.f, 0.f, 0.f, 0.f);
        for (int i = threadIdx.x; i < (WINF + 3) / 4 + 1; i += NTHR) z4[i] = z;
        if (threadIdx.x == 0) qcount = 0;
    }
    // means: waves 0..2 each reduce one channel's 128 partials (deterministic)
    if (threadIdx.x < 192) {
        const int c = threadIdx.x >> 6;      // 0..2
        const int l = threadIdx.x & 63;
        const float* p = ws + SUMS_OFF + (n * 3 + c) * 128;
        float s = p[l] + p[l + 64];
        #pragma unroll
        for (int off = 32; off > 0; off >>= 1) s += __shfl_down(s, off, 64);
        if (l == 0) smean[c] = s * (1.0f / (float)NP);
    }
    __syncthreads();
    const float m0 = smean[0], m1 = smean[1], m2 = smean[2];

    // ---- deposit phase: 512 threads x 8 particles ----
    const int i0 = threadIdx.x * 8;
    const int lw0 = i0 & 15;
    const int lh  = (i0 >> 4) & 15;
    const int ld  = i0 >> 8;
    const int gd = tz * TS + ld, gh = ty * TS + lh, gw0 = tx * TS + lw0;
    const size_t prow = ((size_t)gd * NDIM + gh) * NDIM + gw0;

    const float4* x4 = (const float4*)(x + (size_t)n * 4 * NP);
    const size_t q = prow >> 2;
    const size_t s4 = NP / 4;
    float4 a0 = x4[0 * s4 + q], a1 = x4[0 * s4 + q + 1];
    float4 b0 = x4[1 * s4 + q], b1 = x4[1 * s4 + q + 1];
    float4 c0 = x4[2 * s4 + q], c1 = x4[2 * s4 + q + 1];
    float4 e0 = x4[3 * s4 + q], e1 = x4[3 * s4 + q + 1];
    const float D0[8] = {a0.x, a0.y, a0.z, a0.w, a1.x, a1.y, a1.z, a1.w};
    const float D1[8] = {b0.x, b0.y, b0.z, b0.w, b1.x, b1.y, b1.z, b1.w};
    const float D2[8] = {c0.x, c0.y, c0.z, c0.w, c1.x, c1.y, c1.z, c1.w};
    const float VV[8] = {e0.x, e0.y, e0.z, e0.w, e1.x, e1.y, e1.z, e1.w};

    const int od = tz * TS - LO, oh = ty * TS - LO, ow = tx * TS - LO;
    float* sp = out + (size_t)n * NP;

    #pragma unroll
    for (int k = 0; k < 8; ++k) {
        const float pd = (D0[k] - m0) * DIS_NORM + (float)gd + 0.5f;
        const float ph = (D1[k] - m1) * DIS_NORM + (float)gh + 0.5f;
        const float pw = (D2[k] - m2) * DIS_NORM + (float)(gw0 + k) + 0.5f;
        const float v = VV[k];

        const float fd = floorf(pd), fh = floorf(ph), fw = floorf(pw);
        const int id = (int)fd, ih = (int)fh, iw = (int)fw;
        const float rd = pd - fd, rh = ph - fh, rw = pw - fw;

        const int wd = id - od, wh = ih - oh, ww = iw - ow;
        if ((unsigned)wd <= WIN - 2 && (unsigned)wh <= WIN - 2 &&
            (unsigned)ww <= WIN - 2) {
            const int b00 = (wd * WIN + wh) * WIN + ww;
            const float sd0 = v * (1.0f - rd), sd1 = v * rd;
            const float h0 = 1.0f - rh, h1 = rh;
            const float q0 = 1.0f - rw, q1 = rw;
            deposit_pair(winU, b00,              sd0 * h0 * q0, sd0 * h0 * q1);
            deposit_pair(winU, b00 + WIN,        sd0 * h1 * q0, sd0 * h1 * q1);
            deposit_pair(winU, b00 + WIN2,       sd1 * h0 * q0, sd1 * h0 * q1);
            deposit_pair(winU, b00 + WIN2 + WIN, sd1 * h1 * q0, sd1 * h1 * q1);
        } else {
            const int qi = atomicAdd(&qcount, 1);
            if (qi < QCAP) queue[qi] = (unsigned short)(i0 + k);
            else slow_deposit(winU, sp, pd, ph, pw, v, od, oh, ow);
        }
    }

    __syncthreads();

    // ---- drain spill queue: all lanes active, ~98 entries/block ----
    {
        const int nq = min(qcount, QCAP);
        const float* xb = x + (size_t)n * 4 * NP;
        for (int qi = threadIdx.x; qi < nq; qi += NTHR) {
            const int p = queue[qi];
            const int lw = p & 15, lhq = (p >> 4) & 15, ldq = p >> 8;
            const int gdq = tz * TS + ldq, ghq = ty * TS + lhq, gwq = tx * TS + lw;
            const size_t pr = ((size_t)gdq * NDIM + ghq) * NDIM + gwq;
            const float pd = (xb[pr] - m0) * DIS_NORM + (float)gdq + 0.5f;
            const float ph = (xb[(size_t)NP + pr] - m1) * DIS_NORM + (float)ghq + 0.5f;
            const float pw = (xb[2 * (size_t)NP + pr] - m2) * DIS_NORM + (float)gwq + 0.5f;
            const float v = xb[3 * (size_t)NP + pr];
            slow_deposit(winU, sp, pd, ph, pw, v, od, oh, ow);
        }
    }
    __syncthreads();

    // ---- decode pass: in-place u64 fixed-point -> 2x fp32 (no races) ----
    {
        const int NU = (WINF + 1) / 2;   // 9842
        for (int i = threadIdx.x; i < NU; i += NTHR) {
            const unsigned long long u = winU[i];
            const int lo = (int)(unsigned)(u & 0xffffffffull);
            const int hi = (int)(u >> 32) + (lo < 0 ? 1 : 0);
            float2 f;
            f.x = (float)lo * FXINV;
            f.y = (float)hi * FXINV;
            ((float2*)winU)[i] = f;
        }
    }
    __syncthreads();
    const float* winF = (const float*)winU;

    // ---- flush (fp16): one thread per (lz,ly) row; 3 fixed x-segments ----
    const int EXTY[3] = {6, 16, 5};
    const int nbase = n << 9;
    for (int r = threadIdx.x; r < WIN2; r += NTHR) {
        const int lz = r / WIN;
        const int ly = r - lz * WIN;
        int mz, pz;
        if (lz < LO) { mz = -1; pz = lz; }
        else if (lz < LO + TS) { mz = 0; pz = lz - LO; }
        else { mz = 1; pz = lz - LO - TS; }
        int my, py;
        if (ly < LO) { my = -1; py = ly; }
        else if (ly < LO + TS) { my = 0; py = ly - LO; }
        else { my = 1; py = ly - LO - TS; }
        const int dtz = tz + mz, dty = ty + my;
        if ((unsigned)dtz >= TPB || (unsigned)dty >= TPB) continue;

        const int jz = 1 - mz, jy = 1 - my;
        const int ey = EXTY[jy];
        const int rowoff = pz * ey + py;
        const int pobase = jz * 9 + jy * 3;
        const float* src = winF + r * WIN;
        const int slabRow = nbase + (dtz * 8 + dty) * 8;

        // seg A: jx=2 (dest tile tx-1), lx 0..4, ex=5, scalar half stores
        if (tx > 0) {
            __half* d = slabs + (size_t)(slabRow + tx - 1) * SLABH
                      + BASE27[pobase + 2] + rowoff * 5;
            #pragma unroll
            for (int k = 0; k < 5; ++k) d[k] = __float2half_rn(src[k]);
        }
        // seg B: jx=1 (own tile), lx 5..20, ex=16, two aligned uint4 stores
        {
            __half* d = slabs + (size_t)(slabRow + tx) * SLABH
                      + BASE27[pobase + 1] + rowoff * 16;
            union { uint4 u; __half2 h[4]; } p0, p1;
            #pragma unroll
            for (int k = 0; k < 4; ++k)
                p0.h[k] = __floats2half2_rn(src[5 + 2 * k], src[6 + 2 * k]);
            #pragma unroll
            for (int k = 0; k < 4; ++k)
                p1.h[k] = __floats2half2_rn(src[13 + 2 * k], src[14 + 2 * k]);
            ((uint4*)d)[0] = p0.u;
            ((uint4*)d)[1] = p1.u;
        }
        // seg C: jx=0 (dest tile tx+1), lx 21..26, ex=6, three half2 stores
        if (tx < TPB - 1) {
            __half* d = slabs + (size_t)(slabRow + tx + 1) * SLABH
                      + BASE27[pobase + 0] + rowoff * 6;
            __half2* d2 = (__half2*)d;
            d2[0] = __floats2half2_rn(src[21], src[22]);
            d2[1] = __floats2half2_rn(src[23], src[24]);
            d2[2] = __floats2half2_rn(src[25], src[26]);
        }
    }
}

// 4 consecutive halves (8B aligned) -> float4
__device__ __forceinline__ float4 ldh4(const __half* p) {
    const uint2 u = *(const uint2*)p;
    const __half2 h0 = *(const __half2*)&u.x;
    const __half2 h1 = *(const __half2*)&u.y;
    return make_float4(__low2float(h0), __high2float(h0),
                       __low2float(h1), __high2float(h1));
}

// ---------------------------------------------------------------------------
// Kernel 3: gather, float4 per-quad from fp16 slabs. One thread handles 4
// x-consecutive output cells; ext-16 pieces load 4 halves via uint2 (8B
// aligned: piece bases are x8-half-padded, row stride 16 halves); x-halo
// elements add scalar halves. out RMW is one float4.
//
// Dest-local coverage: j=0 piece (src d-1) covers c in [0,6), p=c, ext 6;
// j=1 own covers [0,16), ext 16; j=2 (src d+1) covers [11,16), p=c-11, ext 5.
// ---------------------------------------------------------------------------
__global__ __launch_bounds__(NTHR) void gather_tile_kernel(const __half* __restrict__ slabs,
                                                           float* __restrict__ out) {
    const int blk = blockIdx.x;              // 0 .. 2*NTILE-1
    const int n = blk >> 9;
    const int t = blk & (NTILE - 1);
    const int tx = t & 7, ty = (t >> 3) & 7, tz = t >> 6;

    const __half* __restrict__ slab = slabs + (size_t)blk * SLABH;
    float4* __restrict__ o4 = (float4*)(out + (size_t)n * NP);

    for (int i4 = threadIdx.x; i4 < TS * TS * TS / 4; i4 += NTHR) {
        const int xq = i4 & 3, y = (i4 >> 2) & 15, z = i4 >> 6;

        int ysec = 0, yp = 0, ye = 0; bool y2 = false;
        if (y < 6)        { if (ty > 0)       { ysec = 0; yp = y;      ye = 6; y2 = true; } }
        else if (y >= 11) { if (ty < TPB - 1) { ysec = 6; yp = y - 11; ye = 5; y2 = true; } }
        int zsec = 0, zp = 0; bool z2 = false;
        if (z < 6)        { if (tz > 0)       { zsec = 0;  zp = z;      z2 = true; } }
        else if (z >= 11) { if (tz < TPB - 1) { zsec = 18; zp = z - 11; z2 = true; } }

        const int rC = z * 16 + y;
        float4 s = ldh4(slab + BASE27[13] + rC * 16 + xq * 4);
        int rY = 0, rZ = 0, rYZ = 0;
        if (y2) {
            rY = z * ye + yp;
            const float4 v = ldh4(slab + BASE27[10 + ysec] + rY * 16 + xq * 4);
            s.x += v.x; s.y += v.y; s.z += v.z; s.w += v.w;
        }
        if (z2) {
            rZ = zp * 16 + y;
            const float4 v = ldh4(slab + BASE27[zsec + 4] + rZ * 16 + xq * 4);
            s.x += v.x; s.y += v.y; s.z += v.z; s.w += v.w;
            if (y2) {
                rYZ = zp * ye + yp;
                const float4 v2 = ldh4(slab + BASE27[zsec + ysec + 1] + rYZ * 16 + xq * 4);
                s.x += v2.x; s.y += v2.y; s.z += v2.z; s.w += v2.w;
            }
        }

        float se[4] = {s.x, s.y, s.z, s.w};
        #pragma unroll
        for (int e = 0; e < 4; ++e) {
            const int xx = xq * 4 + e;
            int xsec = 0, xp = 0, xe = 0; bool x2 = false;
            if (xx < 6)        { if (tx > 0)       { xsec = 0; xp = xx;      xe = 6; x2 = true; } }
            else if (xx >= 11) { if (tx < TPB - 1) { xsec = 2; xp = xx - 11; xe = 5; x2 = true; } }
            if (x2) {
                se[e] += __half2float(slab[BASE27[12 + xsec] + rC * xe + xp]);
                if (y2) se[e] += __half2float(slab[BASE27[9 + ysec + xsec] + rY * xe + xp]);
                if (z2) {
                    se[e] += __half2float(slab[BASE27[zsec + 3 + xsec] + rZ * xe + xp]);
                    if (y2) se[e] += __half2float(slab[BASE27[zsec + ysec + xsec] + rYZ * xe + xp]);
                }
            }
        }

        const size_t grow = ((size_t)(tz * TS + z) * NDIM + ty * TS + y) * (NDIM / 4)
                          + tx * 4 + xq;
        float4 o = o4[grow];
        o.x += se[0]; o.y += se[1]; o.z += se[2]; o.w += se[3];
        o4[grow] = o;
    }
}

// ---------------------------------------------------------------------------
// Fallback (small ws): direct device-scope atomic scatter into out
// ---------------------------------------------------------------------------
__global__ __launch_bounds__(256) void scatter_direct_kernel(const float* __restrict__ x,
                                                             const float* __restrict__ ws,
                                                             float* __restrict__ out) {
    const int lin = blockIdx.x * 256 + threadIdx.x;
    const int n = lin >> 21;
    const int p = lin & (NP - 1);

    float m0, m1, m2;
    load_means128(ws, n, m0, m1, m2);

    const size_t base = (size_t)n * 4 * NP;
    const float d0 = x[base + 0 * (size_t)NP + p];
    const float d1 = x[base + 1 * (size_t)NP + p];
    const float d2 = x[base + 2 * (size_t)NP + p];
    const float v  = x[base + 3 * (size_t)NP + p];

    const int w = p & 127, h = (p >> 7) & 127, d = p >> 14;
    const float pd = (d0 - m0) * DIS_NORM + (float)d + 0.5f;
    const float ph = (d1 - m1) * DIS_NORM + (float)h + 0.5f;
    const float pw = (d2 - m2) * DIS_NORM + (float)w + 0.5f;
    const float fd = floorf(pd), fh = floorf(ph), fw = floorf(pw);
    const int id = (int)fd, ih = (int)fh, iw = (int)fw;
    const float rd = pd - fd, rh = ph - fh, rw = pw - fw;
    const float wd[2] = {1.0f - rd, rd}, wh[2] = {1.0f - rh, rh}, ww[2] = {1.0f - rw, rw};
    float* o = out + (size_t)n * NP;
    #pragma unroll
    for (int dd = 0; dd < 2; ++dd) {
        const int td = id + dd;
        if ((unsigned)td >= (unsigned)NDIM) continue;
        #pragma unroll
        for (int hh = 0; hh < 2; ++hh) {
            const int th = ih + hh;
            if ((unsigned)th >= (unsigned)NDIM) continue;
            const float vdh = v * wd[dd] * wh[hh];
            const int rowbase = (td * NDIM + th) * NDIM;
            #pragma unroll
            for (int wi = 0; wi < 2; ++wi) {
                const int tw = iw + wi;
                if ((unsigned)tw >= (unsigned)NDIM) continue;
                atomicAdd(o + rowbase + tw, vdh * ww[wi]);
            }
        }
    }
}

extern "C" void kernel_launch(void* const* d_in, const int* in_sizes, int n_in,
                              void* d_out, int out_size, void* d_ws, size_t ws_size,
                              hipStream_t stream) {
    const float* x = (const float*)d_in[0];
    float* out = (float*)d_out;
    float* ws = (float*)d_ws;
    __half* slabs = (__half*)(ws + SLABS_OFF);

    dim3 pgrid(128, 7);   // 6 sum planes + 1 out-zero plane

    if (ws_size >= WS_NEEDED_BYTES) {
        prep_kernel<<<pgrid, 256, 0, stream>>>(x, ws, out);
        scatter_tile_kernel<<<dim3(NBATCH * NTILE), NTHR, 0, stream>>>(x, ws, slabs, out);
        gather_tile_kernel<<<dim3(NBATCH * NTILE), NTHR, 0, stream>>>(slabs, out);
    } else {
        prep_kernel<<<pgrid, 256, 0, stream>>>(x, ws, out);
        scatter_direct_kernel<<<dim3(NBATCH * NP / 256), 256, 0, stream>>>(x, ws, out);
    }
}

// Round 10
// 165.966 us; speedup vs baseline: 1.2759x; 1.0609x over previous
//
#include <hip/hip_runtime.h>
#include <hip/hip_fp16.h>

// Problem constants (fixed by reference: x is (2, 4, 128, 128, 128) fp32)
#define NBATCH 2
#define NDIM   128
#define NP     (128 * 128 * 128)        // particles per batch = mesh cells (2^21)
#define DIS_NORM 3.072f                  // 6 * 512 / 1000

// Tiling: 16^3 origin tiles; LDS window halo LO=5 below, HI=6 above.
// WIN=27 -> 19683 cells as PACKED u64 pairs (2 cells/word), 2^-24 fixed point,
// native u64 LDS atomics. Measured design decisions:
//  - fp32 LDS atomicAdd is a CAS loop: 2.7x slower (r3)
//  - WIN=23 (3 blocks/CU) spill blowup: +47us (r4)
//  - direct global-atomic window flush: +57us (r6)
//  - cooperative fusion pins streaming phases at 2 blocks/CU: 272us (r8)
//  - fp16 slabs: -10us, absmax 0.031 vs 0.10 threshold (r9)
// This round: (1) spill queue carries float4(pos,val) -- no scattered drain
// re-reads; (2) u64 decode fused into flush (drops a pass + barrier);
// (3) XCD-chunked blockIdx swizzle, identical in scatter+gather, so slabs are
// produced and consumed on the same XCD's L2.
#define TS   16
#define LO   5
#define HI   6
#define WIN  (TS + LO + HI)              // 27
#define WIN2 (WIN * WIN)                 // 729
#define WINF (WIN * WIN * WIN)           // 19683
#define TPB  8
#define NTILE (TPB * TPB * TPB)          // 512 tiles per batch
#define NTHR 512

#define FXSCALE 16777216.0f              // 2^24
#define FXINV   (1.0f / 16777216.0f)

// Spill queue (float4 entries): expected ~98/block (2.4% of 4096, sigma 9.8);
// 176 = 8 sigma; overflow handled inline. 176*16 = 2816 B.
#define QCAP 176

// Destination-major inbox in fp16: 27 pieces (extents by j: {6,16,5}),
// piece bases padded to 8 halves (16B). Slab = 19704 halves (39408 B).
#define SLABH 19704

// ws layout (floats): [0..1024) partial sums; [1024..) per-tile fp16 slabs
#define SUMS_OFF 0
#define SLABS_OFF 1024
#define WS_FLOATS ((size_t)SLABS_OFF + (size_t)NBATCH * NTILE * SLABH / 2)
#define WS_NEEDED_BYTES (WS_FLOATS * sizeof(float))

// Cumulative piece bases (in HALVES) for extents e={6,16,5}, pad-to-8.
__device__ __constant__ int BASE27[27] = {
    0,216,792,976,1552,3088,3568,3752,4232,
    4384,4960,6496,6976,8512,12608,13888,14368,15648,
    16048,16232,16712,16864,17344,18624,19024,19176,19576};

// ---------------------------------------------------------------------------
// Kernel 1: prep. Planes 0..5: per-block partial sums of displacement
// channels. Plane 6: zero d_out (float spill deposits land there atomically).
// ---------------------------------------------------------------------------
__global__ __launch_bounds__(256) void prep_kernel(const float* __restrict__ x,
                                                   float* __restrict__ ws,
                                                   float* __restrict__ out) {
    const int plane = blockIdx.y;
    if (plane < 6) {
        const int n = plane / 3, c = plane % 3;
        const float4* xp = (const float4*)(x + ((size_t)n * 4 + c) * NP);
        float s = 0.0f;
        for (int i = blockIdx.x * 256 + threadIdx.x; i < NP / 4; i += 128 * 256) {
            float4 v = xp[i];
            s += (v.x + v.y) + (v.z + v.w);
        }
        #pragma unroll
        for (int off = 32; off > 0; off >>= 1) s += __shfl_down(s, off, 64);
        __shared__ float wsum[4];
        if ((threadIdx.x & 63) == 0) wsum[threadIdx.x >> 6] = s;
        __syncthreads();
        if (threadIdx.x == 0)
            ws[SUMS_OFF + plane * 128 + blockIdx.x] =
                (wsum[0] + wsum[1]) + (wsum[2] + wsum[3]);
    } else {
        float4* o4 = (float4*)out;
        const float4 z = make_float4(0.f, 0.f, 0.f, 0.f);
        for (int i = blockIdx.x * 256 + threadIdx.x; i < NBATCH * NP / 4; i += 128 * 256)
            o4[i] = z;
    }
}

// Fallback-path means (serial 128-sum; only used by scatter_direct_kernel).
__device__ __forceinline__ void load_means128(const float* __restrict__ ws, int n,
                                              float& m0, float& m1, float& m2) {
    float s0 = 0.f, s1 = 0.f, s2 = 0.f;
    const float* p0 = ws + SUMS_OFF + (n * 3 + 0) * 128;
    const float* p1 = ws + SUMS_OFF + (n * 3 + 1) * 128;
    const float* p2 = ws + SUMS_OFF + (n * 3 + 2) * 128;
    #pragma unroll 4
    for (int b = 0; b < 128; ++b) { s0 += p0[b]; s1 += p1[b]; s2 += p2[b]; }
    const float inv_np = 1.0f / (float)NP;
    m0 = s0 * inv_np; m1 = s1 * inv_np; m2 = s2 * inv_np;
}

// Packed pair deposit: cells (b, b+1) get (va, vb) in 2^-24 fixed point.
__device__ __forceinline__ void deposit_pair(unsigned long long* __restrict__ winU,
                                             int b, float va, float vb) {
    const int fa = __float2int_rn(va * FXSCALE);
    const int fb = __float2int_rn(vb * FXSCALE);
    const bool odd = (b & 1);
    const long long packed = (((long long)fb) << 32) + (long long)fa;
    const long long hiOnly = ((long long)fa) << 32;
    atomicAdd(&winU[b >> 1], (unsigned long long)(odd ? hiOnly : packed));
    if (odd) atomicAdd(&winU[(b >> 1) + 1], (unsigned long long)(long long)fb);
}

// General-case deposit: window cells -> packed u64 LDS atomics; in-mesh but
// out-of-window -> float global atomics on out (native on gfx950).
__device__ __forceinline__ void slow_deposit(unsigned long long* __restrict__ winU,
                                             float* __restrict__ sp,
                                             float pd, float ph, float pw, float v,
                                             int od, int oh, int ow) {
    const float fd = floorf(pd), fh = floorf(ph), fw = floorf(pw);
    const int id = (int)fd, ih = (int)fh, iw = (int)fw;
    const float rd = pd - fd, rh = ph - fh, rw = pw - fw;
    const int wd = id - od, wh = ih - oh, ww = iw - ow;
    const float wd2[2] = {1.0f - rd, rd};
    const float wh2[2] = {1.0f - rh, rh};
    const float ww2[2] = {1.0f - rw, rw};
    #pragma unroll
    for (int dd = 0; dd < 2; ++dd) {
        const int td = id + dd, wdc = wd + dd;
        const bool dW = (unsigned)wdc < WIN, dM = (unsigned)td < NDIM;
        if (!dM && !dW) continue;
        #pragma unroll
        for (int hh = 0; hh < 2; ++hh) {
            const int th = ih + hh, whc = wh + hh;
            const bool hW = (unsigned)whc < WIN, hM = (unsigned)th < NDIM;
            const float vdh = v * wd2[dd] * wh2[hh];
            #pragma unroll
            for (int wi = 0; wi < 2; ++wi) {
                const int tw = iw + wi, wwc = ww + wi;
                const bool wW = (unsigned)wwc < WIN, wM = (unsigned)tw < NDIM;
                const float dep = vdh * ww2[wi];
                if (dW && hW && wW) {
                    const int cb = (wdc * WIN + whc) * WIN + wwc;
                    const int fx = __float2int_rn(dep * FXSCALE);
                    const long long cv = (cb & 1)
                        ? (((long long)fx) << 32) : (long long)fx;
                    atomicAdd(&winU[cb >> 1], (unsigned long long)cv);
                } else if (dM && hM && wM) {
                    atomicAdd(sp + ((size_t)td * NDIM + th) * NDIM + tw, dep);
                }
            }
        }
    }
}

// ---------------------------------------------------------------------------
// Kernel 2: tiled CIC scatter + destination-major fp16 flush.
// ---------------------------------------------------------------------------
__global__ __launch_bounds__(NTHR, 4) void scatter_tile_kernel(
        const float* __restrict__ x, const float* __restrict__ ws,
        __half* __restrict__ slabs, float* __restrict__ out) {
    // XCD-chunked swizzle (bijective: 1024 blocks, 8 XCDs): same map as gather
    const int blk = ((blockIdx.x & 7) << 7) | (blockIdx.x >> 3);
    const int n = blk >> 9;
    const int t = blk & (NTILE - 1);
    const int tx = t & 7, ty = (t >> 3) & 7, tz = t >> 6;

    __shared__ ulonglong2 win2[(WINF + 3) / 4 + 1];   // 78752 B
    __shared__ float smean[3];
    __shared__ int qcount;
    __shared__ float4 queue[QCAP];                    // 2816 B (pos+val)
    unsigned long long* winU = (unsigned long long*)win2;
    {
        float4* z4 = (float4*)win2;
        const float4 z = make_float4(0.f, 0.f, 0.f, 0.f);
        for (int i = threadIdx.x; i < (WINF + 3) / 4 + 1; i += NTHR) z4[i] = z;
        if (threadIdx.x == 0) qcount = 0;
    }
    // means: waves 0..2 each reduce one channel's 128 partials (deterministic)
    if (threadIdx.x < 192) {
        const int c = threadIdx.x >> 6;      // 0..2
        const int l = threadIdx.x & 63;
        const float* p = ws + SUMS_OFF + (n * 3 + c) * 128;
        float s = p[l] + p[l + 64];
        #pragma unroll
        for (int off = 32; off > 0; off >>= 1) s += __shfl_down(s, off, 64);
        if (l == 0) smean[c] = s * (1.0f / (float)NP);
    }
    __syncthreads();
    const float m0 = smean[0], m1 = smean[1], m2 = smean[2];

    // ---- deposit phase: 512 threads x 8 particles ----
    const int i0 = threadIdx.x * 8;
    const int lw0 = i0 & 15;
    const int lh  = (i0 >> 4) & 15;
    const int ld  = i0 >> 8;
    const int gd = tz * TS + ld, gh = ty * TS + lh, gw0 = tx * TS + lw0;
    const size_t prow = ((size_t)gd * NDIM + gh) * NDIM + gw0;

    const float4* x4 = (const float4*)(x + (size_t)n * 4 * NP);
    const size_t q = prow >> 2;
    const size_t s4 = NP / 4;
    float4 a0 = x4[0 * s4 + q], a1 = x4[0 * s4 + q + 1];
    float4 b0 = x4[1 * s4 + q], b1 = x4[1 * s4 + q + 1];
    float4 c0 = x4[2 * s4 + q], c1 = x4[2 * s4 + q + 1];
    float4 e0 = x4[3 * s4 + q], e1 = x4[3 * s4 + q + 1];
    const float D0[8] = {a0.x, a0.y, a0.z, a0.w, a1.x, a1.y, a1.z, a1.w};
    const float D1[8] = {b0.x, b0.y, b0.z, b0.w, b1.x, b1.y, b1.z, b1.w};
    const float D2[8] = {c0.x, c0.y, c0.z, c0.w, c1.x, c1.y, c1.z, c1.w};
    const float VV[8] = {e0.x, e0.y, e0.z, e0.w, e1.x, e1.y, e1.z, e1.w};

    const int od = tz * TS - LO, oh = ty * TS - LO, ow = tx * TS - LO;
    float* sp = out + (size_t)n * NP;

    #pragma unroll
    for (int k = 0; k < 8; ++k) {
        const float pd = (D0[k] - m0) * DIS_NORM + (float)gd + 0.5f;
        const float ph = (D1[k] - m1) * DIS_NORM + (float)gh + 0.5f;
        const float pw = (D2[k] - m2) * DIS_NORM + (float)(gw0 + k) + 0.5f;
        const float v = VV[k];

        const float fd = floorf(pd), fh = floorf(ph), fw = floorf(pw);
        const int id = (int)fd, ih = (int)fh, iw = (int)fw;
        const float rd = pd - fd, rh = ph - fh, rw = pw - fw;

        const int wd = id - od, wh = ih - oh, ww = iw - ow;
        if ((unsigned)wd <= WIN - 2 && (unsigned)wh <= WIN - 2 &&
            (unsigned)ww <= WIN - 2) {
            const int b00 = (wd * WIN + wh) * WIN + ww;
            const float sd0 = v * (1.0f - rd), sd1 = v * rd;
            const float h0 = 1.0f - rh, h1 = rh;
            const float q0 = 1.0f - rw, q1 = rw;
            deposit_pair(winU, b00,              sd0 * h0 * q0, sd0 * h0 * q1);
            deposit_pair(winU, b00 + WIN,        sd0 * h1 * q0, sd0 * h1 * q1);
            deposit_pair(winU, b00 + WIN2,       sd1 * h0 * q0, sd1 * h0 * q1);
            deposit_pair(winU, b00 + WIN2 + WIN, sd1 * h1 * q0, sd1 * h1 * q1);
        } else {
            const int qi = atomicAdd(&qcount, 1);
            if (qi < QCAP) queue[qi] = make_float4(pd, ph, pw, v);
            else slow_deposit(winU, sp, pd, ph, pw, v, od, oh, ow);
        }
    }

    __syncthreads();

    // ---- drain spill queue: all lanes active, ~98 entries/block ----
    {
        const int nq = min(qcount, QCAP);
        for (int qi = threadIdx.x; qi < nq; qi += NTHR) {
            const float4 e = queue[qi];
            slow_deposit(winU, sp, e.x, e.y, e.z, e.w, od, oh, ow);
        }
    }
    __syncthreads();

    // ---- flush (fp16) with inline u64->f32 decode: one thread per (lz,ly)
    // row. Row r covers cells [r*27, r*27+27) = u64 words [r*27>>1, +14).
    const int EXTY[3] = {6, 16, 5};
    const int nbase = n << 9;
    for (int r = threadIdx.x; r < WIN2; r += NTHR) {
        const int lz = r / WIN;
        const int ly = r - lz * WIN;
        int mz, pz;
        if (lz < LO) { mz = -1; pz = lz; }
        else if (lz < LO + TS) { mz = 0; pz = lz - LO; }
        else { mz = 1; pz = lz - LO - TS; }
        int my, py;
        if (ly < LO) { my = -1; py = ly; }
        else if (ly < LO + TS) { my = 0; py = ly - LO; }
        else { my = 1; py = ly - LO - TS; }
        const int dtz = tz + mz, dty = ty + my;
        if ((unsigned)dtz >= TPB || (unsigned)dty >= TPB) continue;

        // decode this row's 27 cells from 14 words
        const int cbase = r * WIN;
        const int w0 = cbase >> 1;
        const int par = cbase & 1;
        float tmp[28];
        #pragma unroll
        for (int wI = 0; wI < 14; ++wI) {
            const unsigned long long u = winU[w0 + wI];
            const int lo = (int)(unsigned)(u & 0xffffffffull);
            const int hi = (int)(u >> 32) + (lo < 0 ? 1 : 0);
            tmp[2 * wI]     = (float)lo * FXINV;
            tmp[2 * wI + 1] = (float)hi * FXINV;
        }
        const float* src = tmp + par;

        const int jz = 1 - mz, jy = 1 - my;
        const int ey = EXTY[jy];
        const int rowoff = pz * ey + py;
        const int pobase = jz * 9 + jy * 3;
        const int slabRow = nbase + (dtz * 8 + dty) * 8;

        // seg A: jx=2 (dest tile tx-1), lx 0..4, ex=5, scalar half stores
        if (tx > 0) {
            __half* d = slabs + (size_t)(slabRow + tx - 1) * SLABH
                      + BASE27[pobase + 2] + rowoff * 5;
            #pragma unroll
            for (int k = 0; k < 5; ++k) d[k] = __float2half_rn(src[k]);
        }
        // seg B: jx=1 (own tile), lx 5..20, ex=16, two aligned uint4 stores
        {
            __half* d = slabs + (size_t)(slabRow + tx) * SLABH
                      + BASE27[pobase + 1] + rowoff * 16;
            union { uint4 u; __half2 h[4]; } p0, p1;
            #pragma unroll
            for (int k = 0; k < 4; ++k)
                p0.h[k] = __floats2half2_rn(src[5 + 2 * k], src[6 + 2 * k]);
            #pragma unroll
            for (int k = 0; k < 4; ++k)
                p1.h[k] = __floats2half2_rn(src[13 + 2 * k], src[14 + 2 * k]);
            ((uint4*)d)[0] = p0.u;
            ((uint4*)d)[1] = p1.u;
        }
        // seg C: jx=0 (dest tile tx+1), lx 21..26, ex=6, three half2 stores
        if (tx < TPB - 1) {
            __half* d = slabs + (size_t)(slabRow + tx + 1) * SLABH
                      + BASE27[pobase + 0] + rowoff * 6;
            __half2* d2 = (__half2*)d;
            d2[0] = __floats2half2_rn(src[21], src[22]);
            d2[1] = __floats2half2_rn(src[23], src[24]);
            d2[2] = __floats2half2_rn(src[25], src[26]);
        }
    }
}

// 4 consecutive halves (8B aligned) -> float4
__device__ __forceinline__ float4 ldh4(const __half* p) {
    const uint2 u = *(const uint2*)p;
    const __half2 h0 = *(const __half2*)&u.x;
    const __half2 h1 = *(const __half2*)&u.y;
    return make_float4(__low2float(h0), __high2float(h0),
                       __low2float(h1), __high2float(h1));
}

// ---------------------------------------------------------------------------
// Kernel 3: gather, float4 per-quad from fp16 slabs. Same XCD swizzle as
// scatter so each tile's slab is read on the XCD whose L2 produced it.
// ---------------------------------------------------------------------------
__global__ __launch_bounds__(NTHR) void gather_tile_kernel(const __half* __restrict__ slabs,
                                                           float* __restrict__ out) {
    const int blk = ((blockIdx.x & 7) << 7) | (blockIdx.x >> 3);
    const int n = blk >> 9;
    const int t = blk & (NTILE - 1);
    const int tx = t & 7, ty = (t >> 3) & 7, tz = t >> 6;

    const __half* __restrict__ slab = slabs + (size_t)blk * SLABH;
    float4* __restrict__ o4 = (float4*)(out + (size_t)n * NP);

    for (int i4 = threadIdx.x; i4 < TS * TS * TS / 4; i4 += NTHR) {
        const int xq = i4 & 3, y = (i4 >> 2) & 15, z = i4 >> 6;

        int ysec = 0, yp = 0, ye = 0; bool y2 = false;
        if (y < 6)        { if (ty > 0)       { ysec = 0; yp = y;      ye = 6; y2 = true; } }
        else if (y >= 11) { if (ty < TPB - 1) { ysec = 6; yp = y - 11; ye = 5; y2 = true; } }
        int zsec = 0, zp = 0; bool z2 = false;
        if (z < 6)        { if (tz > 0)       { zsec = 0;  zp = z;      z2 = true; } }
        else if (z >= 11) { if (tz < TPB - 1) { zsec = 18; zp = z - 11; z2 = true; } }

        const int rC = z * 16 + y;
        float4 s = ldh4(slab + BASE27[13] + rC * 16 + xq * 4);
        int rY = 0, rZ = 0, rYZ = 0;
        if (y2) {
            rY = z * ye + yp;
            const float4 v = ldh4(slab + BASE27[10 + ysec] + rY * 16 + xq * 4);
            s.x += v.x; s.y += v.y; s.z += v.z; s.w += v.w;
        }
        if (z2) {
            rZ = zp * 16 + y;
            const float4 v = ldh4(slab + BASE27[zsec + 4] + rZ * 16 + xq * 4);
            s.x += v.x; s.y += v.y; s.z += v.z; s.w += v.w;
            if (y2) {
                rYZ = zp * ye + yp;
                const float4 v2 = ldh4(slab + BASE27[zsec + ysec + 1] + rYZ * 16 + xq * 4);
                s.x += v2.x; s.y += v2.y; s.z += v2.z; s.w += v2.w;
            }
        }

        float se[4] = {s.x, s.y, s.z, s.w};
        #pragma unroll
        for (int e = 0; e < 4; ++e) {
            const int xx = xq * 4 + e;
            int xsec = 0, xp = 0, xe = 0; bool x2 = false;
            if (xx < 6)        { if (tx > 0)       { xsec = 0; xp = xx;      xe = 6; x2 = true; } }
            else if (xx >= 11) { if (tx < TPB - 1) { xsec = 2; xp = xx - 11; xe = 5; x2 = true; } }
            if (x2) {
                se[e] += __half2float(slab[BASE27[12 + xsec] + rC * xe + xp]);
                if (y2) se[e] += __half2float(slab[BASE27[9 + ysec + xsec] + rY * xe + xp]);
                if (z2) {
                    se[e] += __half2float(slab[BASE27[zsec + 3 + xsec] + rZ * xe + xp]);
                    if (y2) se[e] += __half2float(slab[BASE27[zsec + ysec + xsec] + rYZ * xe + xp]);
                }
            }
        }

        const size_t grow = ((size_t)(tz * TS + z) * NDIM + ty * TS + y) * (NDIM / 4)
                          + tx * 4 + xq;
        float4 o = o4[grow];
        o.x += se[0]; o.y += se[1]; o.z += se[2]; o.w += se[3];
        o4[grow] = o;
    }
}

// ---------------------------------------------------------------------------
// Fallback (small ws): direct device-scope atomic scatter into out
// ---------------------------------------------------------------------------
__global__ __launch_bounds__(256) void scatter_direct_kernel(const float* __restrict__ x,
                                                             const float* __restrict__ ws,
                                                             float* __restrict__ out) {
    const int lin = blockIdx.x * 256 + threadIdx.x;
    const int n = lin >> 21;
    const int p = lin & (NP - 1);

    float m0, m1, m2;
    load_means128(ws, n, m0, m1, m2);

    const size_t base = (size_t)n * 4 * NP;
    const float d0 = x[base + 0 * (size_t)NP + p];
    const float d1 = x[base + 1 * (size_t)NP + p];
    const float d2 = x[base + 2 * (size_t)NP + p];
    const float v  = x[base + 3 * (size_t)NP + p];

    const int w = p & 127, h = (p >> 7) & 127, d = p >> 14;
    const float pd = (d0 - m0) * DIS_NORM + (float)d + 0.5f;
    const float ph = (d1 - m1) * DIS_NORM + (float)h + 0.5f;
    const float pw = (d2 - m2) * DIS_NORM + (float)w + 0.5f;
    const float fd = floorf(pd), fh = floorf(ph), fw = floorf(pw);
    const int id = (int)fd, ih = (int)fh, iw = (int)fw;
    const float rd = pd - fd, rh = ph - fh, rw = pw - fw;
    const float wd[2] = {1.0f - rd, rd}, wh[2] = {1.0f - rh, rh}, ww[2] = {1.0f - rw, rw};
    float* o = out + (size_t)n * NP;
    #pragma unroll
    for (int dd = 0; dd < 2; ++dd) {
        const int td = id + dd;
        if ((unsigned)td >= (unsigned)NDIM) continue;
        #pragma unroll
        for (int hh = 0; hh < 2; ++hh) {
            const int th = ih + hh;
            if ((unsigned)th >= (unsigned)NDIM) continue;
            const float vdh = v * wd[dd] * wh[hh];
            const int rowbase = (td * NDIM + th) * NDIM;
            #pragma unroll
            for (int wi = 0; wi < 2; ++wi) {
                const int tw = iw + wi;
                if ((unsigned)tw >= (unsigned)NDIM) continue;
                atomicAdd(o + rowbase + tw, vdh * ww[wi]);
            }
        }
    }
}

extern "C" void kernel_launch(void* const* d_in, const int* in_sizes, int n_in,
                              void* d_out, int out_size, void* d_ws, size_t ws_size,
                              hipStream_t stream) {
    const float* x = (const float*)d_in[0];
    float* out = (float*)d_out;
    float* ws = (float*)d_ws;
    __half* slabs = (__half*)(ws + SLABS_OFF);

    dim3 pgrid(128, 7);   // 6 sum planes + 1 out-zero plane

    if (ws_size >= WS_NEEDED_BYTES) {
        prep_kernel<<<pgrid, 256, 0, stream>>>(x, ws, out);
        scatter_tile_kernel<<<dim3(NBATCH * NTILE), NTHR, 0, stream>>>(x, ws, slabs, out);
        gather_tile_kernel<<<dim3(NBATCH * NTILE), NTHR, 0, stream>>>(slabs, out);
    } else {
        prep_kernel<<<pgrid, 256, 0, stream>>>(x, ws, out);
        scatter_direct_kernel<<<dim3(NBATCH * NP / 256), 256, 0, stream>>>(x, ws, out);
    }
}